// Round 4
// baseline (1920.655 us; speedup 1.0000x reference)
//
#include <hip/hip_runtime.h>

typedef __bf16 bf16;
typedef __bf16 bf16x8 __attribute__((ext_vector_type(8)));
typedef __bf16 bf16x4 __attribute__((ext_vector_type(4)));
typedef float f32x4 __attribute__((ext_vector_type(4)));

__device__ inline f32x4 mfma16(bf16x8 a, bf16x8 b, f32x4 c) {
    return __builtin_amdgcn_mfma_f32_16x16x32_bf16(a, b, c, 0, 0, 0);
}

// async global->LDS, 16B per lane. LDS dest is wave-uniform base + lane*16.
__device__ __forceinline__ void async_cp16(const void* g, void* l) {
    __builtin_amdgcn_global_load_lds(
        (__attribute__((address_space(1))) char*)g,
        (__attribute__((address_space(3))) char*)l,
        16, 0, 0);
}

// f32 -> bf16 weight conversion, vec4. grid = n/1024 blocks.
__global__ __launch_bounds__(256) void w2b_kernel(const float* __restrict__ s,
                                                  bf16* __restrict__ d)
{
    const size_t i = ((size_t)blockIdx.x * 256 + threadIdx.x) * 4;
    const float4 f = *(const float4*)(s + i);
    bf16x4 t;
    t[0] = (bf16)f.x; t[1] = (bf16)f.y; t[2] = (bf16)f.z; t[3] = (bf16)f.w;
    *(bf16x4*)(d + i) = t;
}

// ---------------------------------------------------------------------------
// 128x128-tile GEMM (2-barrier structure) — kept for small-N GEMMs.
// C(MxN) = A(MxK)bf16 @ B(NxK)bf16^T, f32 accum. EPI1 adds residual.
// ---------------------------------------------------------------------------
template <int EPI>
__global__ __launch_bounds__(256) void gemm_kernel(
    const bf16* __restrict__ A, const bf16* __restrict__ B,
    const float* __restrict__ res, float* __restrict__ Cout,
    int M, int N, int K)
{
    __shared__ bf16 As[128 * 32];
    __shared__ bf16 Bs[128 * 32];
    const int tid = threadIdx.x;
    const int wave = tid >> 6, lane = tid & 63;
    const int quad = lane >> 4, l16 = lane & 15;

    const int nby = M >> 7, nbx = N >> 7;
    const int nwg = nbx * nby;
    int bid = blockIdx.x;
    {
        const int q = nwg >> 3, r = nwg & 7;
        const int x = bid & 7, loc = bid >> 3;
        bid = (x < r ? x * (q + 1) : r * (q + 1) + (x - r) * q) + loc;
    }
    const int pg = nbx << 3;
    const int g = bid / pg, rem = bid - g * pg;
    const int by = (g << 3) + (rem & 7);
    const int bx = rem >> 3;
    const int row0 = by << 7, col0 = bx << 7;
    const int wrow = ((wave >> 1) << 6), wcol = ((wave & 1) << 6);

    f32x4 acc[4][4] = {};

    const bf16* Ag = A + (size_t)(row0 + (tid >> 2)) * K + (tid & 3) * 8;
    const bf16* Bg = B + (size_t)(col0 + (tid >> 2)) * K + (tid & 3) * 8;
    bf16* Asw = As + wave * 512;
    bf16* Bsw = Bs + wave * 512;
    const size_t K64 = (size_t)64 * K;

    for (int kb = 0; kb < K; kb += 32) {
        async_cp16(Ag + kb,        Asw);
        async_cp16(Ag + K64 + kb,  Asw + 2048);
        async_cp16(Bg + kb,        Bsw);
        async_cp16(Bg + K64 + kb,  Bsw + 2048);
        __syncthreads();
        bf16x8 af[4], bfr[4];
#pragma unroll
        for (int i = 0; i < 4; ++i)
            af[i] = *(const bf16x8*)(&As[(wrow + i * 16 + l16) * 32 + quad * 8]);
#pragma unroll
        for (int j = 0; j < 4; ++j)
            bfr[j] = *(const bf16x8*)(&Bs[(wcol + j * 16 + l16) * 32 + quad * 8]);
#pragma unroll
        for (int i = 0; i < 4; ++i)
#pragma unroll
            for (int j = 0; j < 4; ++j)
                acc[i][j] = mfma16(af[i], bfr[j], acc[i][j]);
        __syncthreads();
    }

#pragma unroll
    for (int i = 0; i < 4; ++i) {
        const int row = row0 + wrow + i * 16 + quad * 4;
#pragma unroll
        for (int j = 0; j < 4; ++j) {
            const int col = col0 + wcol + j * 16 + l16;
#pragma unroll
            for (int r = 0; r < 4; ++r) {
                const size_t idx = (size_t)(row + r) * N + col;
                float v = acc[i][j][r];
                if (EPI == 1) Cout[idx] = v + res[idx];
                else          Cout[idx] = v;
            }
        }
    }
}

// ---------------------------------------------------------------------------
// 256x256-tile 4-phase GEMM, v2 schedule. 512 threads = 8 waves (2Mx4N),
// per-wave 128x64 output. BK=64, double-buffered LDS (128 KiB).
// Phase reads rebalanced 8/4/8/4: B-quadrant-0 for tile t+1 is pre-read in
// tile t's phase 3 AFTER vmcnt(6) (data provably landed). Stage placement:
//   p0: stage A[t+1][h1] (into buffer n — not read this tile: safe)
//   p2: stage B[t+2][h0]+[h1] (B[c] readers finished at p1's end barrier)
//   p3: stage A[t+2][h0]  (A[c][h0] readers finished at p2's end barrier)
// (R1-R3 staged B[t+2][h0] in p1 — a latent cross-wave WAR race; fixed here.)
// vmcnt queue at p3: 14 calls; next tile needs oldest 8 -> vmcnt(6).
// ---------------------------------------------------------------------------
template <int EPI>
__global__ __launch_bounds__(512, 2) void gemm256_kernel(
    const bf16* __restrict__ A, const bf16* __restrict__ B,
    const float* __restrict__ res, float* __restrict__ Cout,
    int M, int N, int K)
{
    __shared__ bf16 As[2][2][128][64];
    __shared__ bf16 Bs[2][2][128][64];
    const int tid = threadIdx.x;
    const int wid = tid >> 6, lane = tid & 63;
    const int quad = lane >> 4, l16 = lane & 15;
    const int wm = wid >> 2, wn = wid & 3;
    const int xsw = l16 & 7;
    const int bofs = (wn & 1) * 64;

    const int nby = M >> 8, nbx = N >> 8;
    const int nwg = nbx * nby;
    int bid = blockIdx.x;
    {
        const int q = nwg >> 3, r = nwg & 7;
        const int x = bid & 7, loc = bid >> 3;
        bid = (x < r ? x * (q + 1) : r * (q + 1) + (x - r) * q) + loc;
    }
    const int pg = nbx << 3;
    const int g = bid / pg, rem = bid - g * pg;
    const int by = (g << 3) + (rem & 7);
    const int bx = rem >> 3;
    const int row0 = by << 8, col0 = bx << 8;

    const int srow = tid >> 3;
    const int scol = ((tid & 7) ^ ((tid >> 3) & 7)) * 8;
    const bf16* Abase = A + (size_t)(row0 + srow) * K + scol;
    const bf16* Bbase = B + (size_t)(col0 + srow) * K + scol;
    const size_t K64 = (size_t)K * 64;
    const size_t K128 = (size_t)K * 128;

    f32x4 acc[8][4] = {};

#define STG_A(BUF, HH, KB) do { \
    const bf16* _g = Abase + (size_t)(HH) * K128 + (KB); \
    bf16* _l = &As[BUF][HH][0][0] + wid * 512; \
    async_cp16(_g, _l); \
    async_cp16(_g + K64, _l + 4096); } while (0)
#define STG_B(BUF, HH, KB) do { \
    const bf16* _g = Bbase + (size_t)(HH) * K128 + (KB); \
    bf16* _l = &Bs[BUF][HH][0][0] + wid * 512; \
    async_cp16(_g, _l); \
    async_cp16(_g + K64, _l + 4096); } while (0)

#define READ_A(RH) do { \
    _Pragma("unroll") for (int f = 0; f < 4; ++f) { \
        af[f*2+0] = *(const bf16x8*)(&Ah[(RH)*64 + f*16 + l16][(quad ^ xsw) * 8]); \
        af[f*2+1] = *(const bf16x8*)(&Ah[(RH)*64 + f*16 + l16][((4 + quad) ^ xsw) * 8]); } } while (0)

#define READ_Bp(BP, CH, BF) do { \
    _Pragma("unroll") for (int f = 0; f < 2; ++f) { \
        BF[f*2+0] = *(const bf16x8*)(&BP[bofs + (CH)*32 + f*16 + l16][(quad ^ xsw) * 8]); \
        BF[f*2+1] = *(const bf16x8*)(&BP[bofs + (CH)*32 + f*16 + l16][((4 + quad) ^ xsw) * 8]); } } while (0)

#define MFMA_Q(RH, CH, BF) do { \
    _Pragma("unroll") for (int f = 0; f < 4; ++f) \
    _Pragma("unroll") for (int f2 = 0; f2 < 2; ++f2) { \
        acc[(RH)*4+f][(CH)*2+f2] = mfma16(af[f*2+0], BF[f2*2+0], acc[(RH)*4+f][(CH)*2+f2]); \
        acc[(RH)*4+f][(CH)*2+f2] = mfma16(af[f*2+1], BF[f2*2+1], acc[(RH)*4+f][(CH)*2+f2]); } } while (0)

    const int NT = K >> 6;
    STG_B(0, 0, 0); STG_B(0, 1, 0); STG_A(0, 0, 0); STG_A(0, 1, 0);
    if (NT > 1) {
        STG_B(1, 0, 64); STG_B(1, 1, 64); STG_A(1, 0, 64);
        asm volatile("s_waitcnt vmcnt(6)" ::: "memory");
    } else {
        asm volatile("s_waitcnt vmcnt(0)" ::: "memory");
    }
    __builtin_amdgcn_s_barrier();

    bf16x8 af[8], bf0[4], bf1[4];
    {   // pre-read tile0 B quadrant 0 from buffer 0
        const bf16 (*Bh0)[64] = Bs[0][wn >> 1];
        READ_Bp(Bh0, 0, bf0);
    }
    for (int t = 0; t < NT; ++t) {
        const int c = t & 1, n = c ^ 1;
        const bf16 (*Ah)[64] = As[c][wm];
        const bf16 (*Bh)[64] = Bs[c][wn >> 1];
        const int kb1 = (t + 1) << 6, kb2 = (t + 2) << 6;
        // ---------------- phase 0 (8 ds_reads) ----------------
        READ_A(0);
        if (t + 1 < NT) STG_A(n, 1, kb1);
        __builtin_amdgcn_s_barrier();
        asm volatile("s_waitcnt lgkmcnt(0)" ::: "memory");
        __builtin_amdgcn_sched_barrier(0);
        __builtin_amdgcn_s_setprio(1);
        MFMA_Q(0, 0, bf0);
        __builtin_amdgcn_s_setprio(0);
        __builtin_amdgcn_s_barrier();
        // ---------------- phase 1 (4 ds_reads) ----------------
        READ_Bp(Bh, 1, bf1);
        __builtin_amdgcn_s_barrier();
        asm volatile("s_waitcnt lgkmcnt(0)" ::: "memory");
        __builtin_amdgcn_sched_barrier(0);
        __builtin_amdgcn_s_setprio(1);
        MFMA_Q(0, 1, bf1);
        __builtin_amdgcn_s_setprio(0);
        __builtin_amdgcn_s_barrier();
        // ---------------- phase 2 (8 ds_reads) ----------------
        READ_A(1);
        if (t + 2 < NT) { STG_B(c, 0, kb2); STG_B(c, 1, kb2); }
        __builtin_amdgcn_s_barrier();
        asm volatile("s_waitcnt lgkmcnt(0)" ::: "memory");
        __builtin_amdgcn_sched_barrier(0);
        __builtin_amdgcn_s_setprio(1);
        MFMA_Q(1, 0, bf0);
        __builtin_amdgcn_s_setprio(0);
        __builtin_amdgcn_s_barrier();
        // ---------------- phase 3 (4 ds_reads, post-vmcnt) ----------------
        if (t + 2 < NT) STG_A(c, 0, kb2);
        __builtin_amdgcn_s_barrier();
        __builtin_amdgcn_s_setprio(1);
        MFMA_Q(1, 1, bf1);
        __builtin_amdgcn_s_setprio(0);
        if (t + 2 < NT)      { asm volatile("s_waitcnt vmcnt(6)" ::: "memory"); }
        else if (t + 1 < NT) { asm volatile("s_waitcnt vmcnt(0)" ::: "memory"); }
        if (t + 1 < NT) {   // pre-read next tile's B quadrant 0 (landed above)
            const bf16 (*Bn_)[64] = Bs[n][wn >> 1];
            READ_Bp(Bn_, 0, bf0);
        }
        __builtin_amdgcn_s_barrier();
    }
#undef STG_A
#undef STG_B
#undef READ_A
#undef READ_Bp
#undef MFMA_Q

#pragma unroll
    for (int fr = 0; fr < 8; ++fr) {
        const int row = row0 + wm * 128 + fr * 16 + quad * 4;
#pragma unroll
        for (int fc = 0; fc < 4; ++fc) {
            const int col = col0 + wn * 64 + fc * 16 + l16;
#pragma unroll
            for (int r = 0; r < 4; ++r) {
                const size_t idx = (size_t)(row + r) * N + col;
                float v = acc[fr][fc][r];
                if (EPI == 1) Cout[idx] = v + res[idx];
                else          Cout[idx] = v;
            }
        }
    }
}

// ---------------------------------------------------------------------------
// prenorm+concat: xcat[row,0:1024]=rmsnorm(emb), [1024:2048]=rmsnorm(hid)
// ---------------------------------------------------------------------------
__global__ __launch_bounds__(256) void prenorm_kernel(
    const float* __restrict__ emb, const float* __restrict__ hid,
    const float* __restrict__ we, const float* __restrict__ wh,
    bf16* __restrict__ xcat)
{
    const int rr = blockIdx.x * 4 + (threadIdx.x >> 6);
    const int lane = threadIdx.x & 63;
    const int half = rr & 1, row = rr >> 1;
    const float* x = (half ? hid : emb) + (size_t)row * 1024;
    const float* w = half ? wh : we;
    float4 v[4]; float ss = 0.f;
#pragma unroll
    for (int j = 0; j < 4; ++j) {
        v[j] = *(const float4*)(x + (size_t)(lane + 64 * j) * 4);
        ss += v[j].x * v[j].x + v[j].y * v[j].y + v[j].z * v[j].z + v[j].w * v[j].w;
    }
#pragma unroll
    for (int m = 32; m; m >>= 1) ss += __shfl_xor(ss, m, 64);
    const float rms = rsqrtf(ss * (1.f / 1024.f) + 1e-6f);
    bf16* o = xcat + (size_t)row * 2048 + half * 1024;
#pragma unroll
    for (int j = 0; j < 4; ++j) {
        const int d = (lane + 64 * j) * 4;
        float4 wv = *(const float4*)(w + d);
        bf16x4 t;
        t[0] = (bf16)(v[j].x * rms * wv.x);
        t[1] = (bf16)(v[j].y * rms * wv.y);
        t[2] = (bf16)(v[j].z * rms * wv.z);
        t[3] = (bf16)(v[j].w * rms * wv.w);
        *(bf16x4*)(o + d) = t;
    }
}

// rmsnorm over H=1024, f32 in -> bf16 out, one wave per row
__global__ __launch_bounds__(256) void rmsnorm_kernel(
    const float* __restrict__ xin, const float* __restrict__ w, bf16* __restrict__ out)
{
    const int row = blockIdx.x * 4 + (threadIdx.x >> 6);
    const int lane = threadIdx.x & 63;
    const float* x = xin + (size_t)row * 1024;
    float4 v[4]; float ss = 0.f;
#pragma unroll
    for (int j = 0; j < 4; ++j) {
        v[j] = *(const float4*)(x + (size_t)(lane + 64 * j) * 4);
        ss += v[j].x * v[j].x + v[j].y * v[j].y + v[j].z * v[j].z + v[j].w * v[j].w;
    }
#pragma unroll
    for (int m = 32; m; m >>= 1) ss += __shfl_xor(ss, m, 64);
    const float rms = rsqrtf(ss * (1.f / 1024.f) + 1e-6f);
    bf16* o = out + (size_t)row * 1024;
#pragma unroll
    for (int j = 0; j < 4; ++j) {
        const int d = (lane + 64 * j) * 4;
        float4 wv = *(const float4*)(w + d);
        bf16x4 t;
        t[0] = (bf16)(v[j].x * rms * wv.x);
        t[1] = (bf16)(v[j].y * rms * wv.y);
        t[2] = (bf16)(v[j].z * rms * wv.z);
        t[3] = (bf16)(v[j].w * rms * wv.w);
        *(bf16x4*)(o + d) = t;
    }
}

// ---------------------------------------------------------------------------
// q prep: rmsnorm(D=256) -> rope(first 64, interleaved) -> *1/16 -> bf16
// ---------------------------------------------------------------------------
__global__ __launch_bounds__(256) void qprep_kernel(
    const float* __restrict__ qg, const float* __restrict__ qn_w, bf16* __restrict__ qa)
{
    const int row = blockIdx.x * 4 + (threadIdx.x >> 6);  // (b*L+l)*8+h
    const int lane = threadIdx.x & 63;
    const int h = row & 7, bl = row >> 3;
    const int l = bl & 2047, b = bl >> 11;
    const float* x = qg + (size_t)row * 512;
    float v[4]; float ss = 0.f;
#pragma unroll
    for (int j = 0; j < 4; ++j) { v[j] = x[lane + 64 * j]; ss += v[j] * v[j]; }
#pragma unroll
    for (int m = 32; m; m >>= 1) ss += __shfl_xor(ss, m, 64);
    const float rms = rsqrtf(ss * (1.f / 256.f) + 1e-6f);
    float y[4];
#pragma unroll
    for (int j = 0; j < 4; ++j) y[j] = v[j] * rms * qn_w[lane + 64 * j];
    {
        const float p = __shfl_xor(y[0], 1, 64);
        const int i2 = lane >> 1;
        const float inv = powf(1e7f, -(float)(2 * i2) * (1.f / 64.f));
        const float ang = (float)l * inv;
        const float c = cosf(ang), s = sinf(ang);
        y[0] = (lane & 1) ? (p * s + y[0] * c) : (y[0] * c - p * s);
    }
    bf16* o = qa + ((size_t)((b * 8 + h) * 2048 + l)) * 256;
#pragma unroll
    for (int j = 0; j < 4; ++j) o[lane + 64 * j] = (bf16)(y[j] * 0.0625f);
}

// k prep: same minus scale; (B,L,NKV,D) f32 -> (B,NKV,L,D) bf16
__global__ __launch_bounds__(256) void kprep_kernel(
    const float* __restrict__ kf, const float* __restrict__ kn_w, bf16* __restrict__ ka)
{
    const int row = blockIdx.x * 4 + (threadIdx.x >> 6);  // (b*L+l)*2+kv
    const int lane = threadIdx.x & 63;
    const int kv = row & 1, bl = row >> 1;
    const int l = bl & 2047, b = bl >> 11;
    const float* x = kf + (size_t)row * 256;
    float v[4]; float ss = 0.f;
#pragma unroll
    for (int j = 0; j < 4; ++j) { v[j] = x[lane + 64 * j]; ss += v[j] * v[j]; }
#pragma unroll
    for (int m = 32; m; m >>= 1) ss += __shfl_xor(ss, m, 64);
    const float rms = rsqrtf(ss * (1.f / 256.f) + 1e-6f);
    float y[4];
#pragma unroll
    for (int j = 0; j < 4; ++j) y[j] = v[j] * rms * kn_w[lane + 64 * j];
    {
        const float p = __shfl_xor(y[0], 1, 64);
        const int i2 = lane >> 1;
        const float inv = powf(1e7f, -(float)(2 * i2) * (1.f / 64.f));
        const float ang = (float)l * inv;
        const float c = cosf(ang), s = sinf(ang);
        y[0] = (lane & 1) ? (p * s + y[0] * c) : (y[0] * c - p * s);
    }
    bf16* o = ka + ((size_t)((b * 2 + kv) * 2048 + l)) * 256;
#pragma unroll
    for (int j = 0; j < 4; ++j) o[lane + 64 * j] = (bf16)y[j];
}

// v prep: (B,L,NKV,D) f32 -> (B,NKV,D,L) bf16 via LDS 64x64 tile transpose.
__global__ __launch_bounds__(256) void vprep_kernel(const float* __restrict__ vf,
                                                    bf16* __restrict__ vt)
{
    __shared__ float t[64][65];
    const int l0 = blockIdx.x << 6;
    const int d0 = blockIdx.y << 6;
    const int b = blockIdx.z >> 1, kv = blockIdx.z & 1;
    const int tx = threadIdx.x & 63, ty = threadIdx.x >> 6;
    const float* src = vf + ((size_t)b * 4096 + kv) * 256;
#pragma unroll
    for (int j = 0; j < 16; ++j) {
        const int l = ty + j * 4;
        t[l][tx] = src[(size_t)(l0 + l) * 512 + d0 + tx];
    }
    __syncthreads();
    bf16* dst = vt + (size_t)(b * 2 + kv) * 256 * 2048;
#pragma unroll
    for (int j = 0; j < 16; ++j) {
        const int d = ty + j * 4;
        dst[(size_t)(d0 + d) * 2048 + l0 + tx] = (bf16)t[tx][d];
    }
}

// ---------------------------------------------------------------------------
// flash attention, balanced pairing + T14 async staging.
// 1 block = (b, h, q-tile pair {j, 31-j}) -> uniform 66 kv-tiles/block.
// Next tile's K/V global loads issue at tile top (regs), LDS write after the
// PV-read barrier: HBM/L2 latency hides under QK+softmax+PV.
// ---------------------------------------------------------------------------
__global__ __launch_bounds__(256) void attn_kernel(
    const bf16* __restrict__ qa, const bf16* __restrict__ ka,
    const bf16* __restrict__ vt, float* __restrict__ of)
{
    __shared__ bf16 Ks[32 * 264];
    __shared__ bf16 Vt[256 * 40];
    __shared__ bf16 Pw[4 * 16 * 40];
    const int tid = threadIdx.x;
    const int wave = tid >> 6, lane = tid & 63;
    const int quad = lane >> 4, l16 = lane & 15;
    const int bid = blockIdx.x;
    const int j = bid & 15, h = (bid >> 4) & 7, b = bid >> 7;
    const int kvh = h >> 2;
    const bf16* qptr = qa + ((size_t)(b * 8 + h)) * 2048 * 256;
    const bf16* kptr = ka + ((size_t)(b * 2 + kvh)) * 2048 * 256;
    const bf16* vptr = vt + ((size_t)(b * 2 + kvh)) * 256 * 2048;
    float* optr = of + ((size_t)(b * 8 + h)) * 2048 * 256;

    for (int s = 0; s < 2; ++s) {
        const int qt = s ? (31 - j) : j;
        const int qbase = qt * 64 + wave * 16;

        bf16x8 qf[8];
#pragma unroll
        for (int db = 0; db < 8; ++db)
            qf[db] = *(const bf16x8*)(qptr + (size_t)(qbase + l16) * 256 + db * 32 + quad * 8);

        f32x4 o_acc[16] = {};
        float m_i[4], l_i[4];
#pragma unroll
        for (int r = 0; r < 4; ++r) { m_i[r] = -1e30f; l_i[r] = 0.f; }

        const int ntiles = qt * 2 + 2;
        // prologue: stage tile 0 directly
#pragma unroll
        for (int c = 0; c < 4; ++c) {
            const int idx = tid + c * 256;
            const int kr = idx >> 5, kc = (idx & 31) * 8;
            *(bf16x8*)(&Ks[kr * 264 + kc]) = *(const bf16x8*)(kptr + (size_t)kr * 256 + kc);
            const int vd = idx >> 2, vc = (idx & 3) * 8;
            *(bf16x8*)(&Vt[vd * 40 + vc]) = *(const bf16x8*)(vptr + (size_t)vd * 2048 + vc);
        }
        __syncthreads();

        for (int kt = 0; kt < ntiles; ++kt) {
            const int kvs = kt * 32;
            const bool pf = (kt + 1 < ntiles);
            bf16x8 kreg[4], vreg[4];
            if (pf) {   // T14: issue next tile's loads early, to registers
                const int kvs1 = kvs + 32;
#pragma unroll
                for (int c = 0; c < 4; ++c) {
                    const int idx = tid + c * 256;
                    const int kr = idx >> 5, kc = (idx & 31) * 8;
                    kreg[c] = *(const bf16x8*)(kptr + (size_t)(kvs1 + kr) * 256 + kc);
                    const int vd = idx >> 2, vc = (idx & 3) * 8;
                    vreg[c] = *(const bf16x8*)(vptr + (size_t)vd * 2048 + kvs1 + vc);
                }
            }

            f32x4 s0 = {}, s1 = {};
#pragma unroll
            for (int db = 0; db < 8; ++db) {
                bf16x8 k0 = *(const bf16x8*)(&Ks[l16 * 264 + db * 32 + quad * 8]);
                bf16x8 k1 = *(const bf16x8*)(&Ks[(16 + l16) * 264 + db * 32 + quad * 8]);
                s0 = mfma16(qf[db], k0, s0);
                s1 = mfma16(qf[db], k1, s1);
            }

            float alpha[4], p0v[4], p1v[4];
#pragma unroll
            for (int r = 0; r < 4; ++r) {
                const int qrow = qbase + quad * 4 + r;
                float a0 = (kvs + l16 > qrow) ? -1e30f : s0[r];
                float a1 = (kvs + 16 + l16 > qrow) ? -1e30f : s1[r];
                float mx = fmaxf(a0, a1);
#pragma unroll
                for (int m = 8; m; m >>= 1) mx = fmaxf(mx, __shfl_xor(mx, m, 64));
                const float mnew = fmaxf(m_i[r], mx);
                const float a = __expf(m_i[r] - mnew);
                const float p0 = __expf(a0 - mnew);
                const float p1 = __expf(a1 - mnew);
                float ps = p0 + p1;
#pragma unroll
                for (int m = 8; m; m >>= 1) ps += __shfl_xor(ps, m, 64);
                l_i[r] = l_i[r] * a + ps;
                m_i[r] = mnew;
                alpha[r] = a; p0v[r] = p0; p1v[r] = p1;
            }
#pragma unroll
            for (int t = 0; t < 16; ++t) {
                f32x4 o = o_acc[t];
                o[0] *= alpha[0]; o[1] *= alpha[1]; o[2] *= alpha[2]; o[3] *= alpha[3];
                o_acc[t] = o;
            }
            bf16* pw = &Pw[wave * 16 * 40];
#pragma unroll
            for (int r = 0; r < 4; ++r) {
                pw[(quad * 4 + r) * 40 + l16]      = (bf16)p0v[r];
                pw[(quad * 4 + r) * 40 + 16 + l16] = (bf16)p1v[r];
            }
            __syncthreads();
            const bf16x8 pa = *(const bf16x8*)(&pw[l16 * 40 + quad * 8]);
#pragma unroll
            for (int t = 0; t < 16; ++t) {
                bf16x8 vfr = *(const bf16x8*)(&Vt[(t * 16 + l16) * 40 + quad * 8]);
                o_acc[t] = mfma16(pa, vfr, o_acc[t]);
            }
            __syncthreads();   // all K/V LDS reads for this tile done

            if (pf) {   // write prefetched tile to LDS
#pragma unroll
                for (int c = 0; c < 4; ++c) {
                    const int idx = tid + c * 256;
                    const int kr = idx >> 5, kc = (idx & 31) * 8;
                    *(bf16x8*)(&Ks[kr * 264 + kc]) = kreg[c];
                    const int vd = idx >> 2, vc = (idx & 3) * 8;
                    *(bf16x8*)(&Vt[vd * 40 + vc]) = vreg[c];
                }
                __syncthreads();
            }
        }

#pragma unroll
        for (int r = 0; r < 4; ++r) {
            const float inv = 1.f / l_i[r];
            const int row = qbase + quad * 4 + r;
#pragma unroll
            for (int t = 0; t < 16; ++t)
                optr[(size_t)row * 256 + t * 16 + l16] = o_acc[t][r] * inv;
        }
        // s=1 prologue LDS writes are safe: all waves passed the final PV
        // barrier of s=0; only global ops occur in between.
    }
}

// gated output: ag[(b,l,h*256+d)] = of[(b,h,l,d)] * sigmoid(qg gate)
__global__ void gating_kernel(const float* __restrict__ of, const float* __restrict__ qg,
                              bf16* __restrict__ ag)
{
    const size_t i = (size_t)blockIdx.x * 256 + threadIdx.x;
    const int d = (int)(i & 255);
    const int h = (int)((i >> 8) & 7);
    const size_t bl = i >> 11;
    const float o = of[((size_t)((bl >> 11) * 8 + h) * 2048 + (bl & 2047)) * 256 + d];
    const float g = qg[(bl * 8 + h) * 512 + 256 + d];
    ag[i] = (bf16)(o * (1.f / (1.f + __expf(-g))));
}

// h = bf16(silu(g) * u)
__global__ void silu_kernel(const float* __restrict__ g, const float* __restrict__ u,
                            bf16* __restrict__ h)
{
    const size_t i = ((size_t)blockIdx.x * 256 + threadIdx.x) * 4;
    const float4 gv = *(const float4*)(g + i);
    const float4 uv = *(const float4*)(u + i);
    bf16x4 t;
    t[0] = (bf16)(gv.x * (1.f / (1.f + __expf(-gv.x))) * uv.x);
    t[1] = (bf16)(gv.y * (1.f / (1.f + __expf(-gv.y))) * uv.y);
    t[2] = (bf16)(gv.z * (1.f / (1.f + __expf(-gv.z))) * uv.z);
    t[3] = (bf16)(gv.w * (1.f / (1.f + __expf(-gv.w))) * uv.w);
    *(bf16x4*)(h + i) = t;
}

// ---------------------------------------------------------------------------
extern "C" void kernel_launch(void* const* d_in, const int* in_sizes, int n_in,
                              void* d_out, int out_size, void* d_ws, size_t ws_size,
                              hipStream_t stream)
{
    const float* emb       = (const float*)d_in[0];
    const float* hid       = (const float*)d_in[1];
    const float* pre_emb_w = (const float*)d_in[2];
    const float* pre_hid_w = (const float*)d_in[3];
    const float* fc_w      = (const float*)d_in[4];
    const float* in_ln_w   = (const float*)d_in[5];
    const float* q_w       = (const float*)d_in[6];
    const float* k_w       = (const float*)d_in[7];
    const float* v_w       = (const float*)d_in[8];
    const float* o_w       = (const float*)d_in[9];
    const float* qn_w      = (const float*)d_in[10];
    const float* kn_w      = (const float*)d_in[11];
    const float* post_ln_w = (const float*)d_in[12];
    const float* gate_w    = (const float*)d_in[13];
    const float* up_w      = (const float*)d_in[14];
    const float* down_w    = (const float*)d_in[15];
    const float* norm_w    = (const float*)d_in[16];
    const float* lm_w      = (const float*)d_in[17];
    float* out = (float*)d_out;
    char* ws = (char*)d_ws;

    // workspace layout (lifetime-overlapped), total 360 MiB (unchanged)
    float* xres = (float*)(ws + 0);                 // 32 MiB, residual (in-place)
    bf16*  xln  = (bf16*)(ws + 33554432);           // 16 MiB, reused 3x
    char*  C    = ws + 50331648;                    // 128 MiB: qg then gate_f32 (+ wb slots)
    char*  D    = ws + 184549376;                   // 128 MiB: xcat/kf/vf/of then up_f32
    char*  E    = ws + 318767104;                   // 56 MiB: qa/ka/va then ag then h
    float* qg   = (float*)C;
    float* gf   = (float*)C;
    bf16*  xcat = (bf16*)D;
    float* kf   = (float*)(D + 33554432);
    float* vf   = (float*)(D + 50331648);
    float* of   = (float*)(D + 67108864);
    float* uf   = (float*)D;
    bf16*  qa   = (bf16*)E;
    bf16*  ka   = (bf16*)(E + 33554432);
    bf16*  va   = (bf16*)(E + 41943040);
    bf16*  ag   = (bf16*)E;
    bf16*  hb   = (bf16*)E;
    // bf16 weight scratch slots (placed in regions dead at time of use)
    bf16*  wbC  = (bf16*)C;                  // fc(4M), o(4M), down(7M), lm(32M)
    bf16*  wbD  = (bf16*)D;                  // q(8M), k(1M), v(1M)
    bf16*  wbDt = (bf16*)(D + 117440512);    // gate(7M), up(7M) — above uf

    prenorm_kernel<<<4096, 256, 0, stream>>>(emb, hid, pre_emb_w, pre_hid_w, xcat);

    w2b_kernel<<<2048, 256, 0, stream>>>(fc_w, wbC);                       // 1024x2048
    gemm_kernel<0><<<512, 256, 0, stream>>>(xcat, wbC, nullptr, xres, 8192, 1024, 2048);
    rmsnorm_kernel<<<2048, 256, 0, stream>>>(xres, in_ln_w, xln);

    w2b_kernel<<<4096, 256, 0, stream>>>(q_w, wbD);                        // 4096x1024
    gemm256_kernel<0><<<512, 512, 0, stream>>>(xln, wbD, nullptr, qg, 8192, 4096, 1024);
    w2b_kernel<<<512, 256, 0, stream>>>(k_w, wbD);                         // 512x1024
    gemm_kernel<0><<<256, 256, 0, stream>>>(xln, wbD, nullptr, kf, 8192, 512, 1024);
    w2b_kernel<<<512, 256, 0, stream>>>(v_w, wbD);
    gemm_kernel<0><<<256, 256, 0, stream>>>(xln, wbD, nullptr, vf, 8192, 512, 1024);

    qprep_kernel<<<16384, 256, 0, stream>>>(qg, qn_w, qa);
    kprep_kernel<<<4096, 256, 0, stream>>>(kf, kn_w, ka);
    vprep_kernel<<<dim3(32, 4, 8), 256, 0, stream>>>(vf, va);
    attn_kernel<<<512, 256, 0, stream>>>(qa, ka, va, of);
    gating_kernel<<<65536, 256, 0, stream>>>(of, qg, ag);

    w2b_kernel<<<2048, 256, 0, stream>>>(o_w, wbC);                        // 1024x2048
    gemm_kernel<1><<<512, 256, 0, stream>>>(ag, wbC, xres, xres, 8192, 1024, 2048);
    rmsnorm_kernel<<<2048, 256, 0, stream>>>(xres, post_ln_w, xln);

    w2b_kernel<<<3584, 256, 0, stream>>>(gate_w, wbDt);                    // 3584x1024
    gemm256_kernel<0><<<448, 512, 0, stream>>>(xln, wbDt, nullptr, gf, 8192, 3584, 1024);
    w2b_kernel<<<3584, 256, 0, stream>>>(up_w, wbDt);
    gemm256_kernel<0><<<448, 512, 0, stream>>>(xln, wbDt, nullptr, uf, 8192, 3584, 1024);
    silu_kernel<<<28672, 256, 0, stream>>>(gf, uf, hb);

    w2b_kernel<<<3584, 256, 0, stream>>>(down_w, wbC);                     // 1024x3584
    gemm_kernel<1><<<512, 256, 0, stream>>>(hb, wbC, xres, xres, 8192, 1024, 3584);
    rmsnorm_kernel<<<2048, 256, 0, stream>>>(xres, norm_w, xln);

    w2b_kernel<<<16384, 256, 0, stream>>>(lm_w, wbC);                      // 16384x1024
    gemm256_kernel<0><<<2048, 512, 0, stream>>>(xln, wbC, nullptr, out, 8192, 16384, 1024);
}

// Round 5
// 1857.596 us; speedup vs baseline: 1.0339x; 1.0339x over previous
//
#include <hip/hip_runtime.h>

typedef __bf16 bf16;
typedef __bf16 bf16x8 __attribute__((ext_vector_type(8)));
typedef __bf16 bf16x4 __attribute__((ext_vector_type(4)));
typedef float f32x4 __attribute__((ext_vector_type(4)));

__device__ inline f32x4 mfma16(bf16x8 a, bf16x8 b, f32x4 c) {
    return __builtin_amdgcn_mfma_f32_16x16x32_bf16(a, b, c, 0, 0, 0);
}

// async global->LDS, 16B per lane. LDS dest is wave-uniform base + lane*16.
__device__ __forceinline__ void async_cp16(const void* g, void* l) {
    __builtin_amdgcn_global_load_lds(
        (__attribute__((address_space(1))) char*)g,
        (__attribute__((address_space(3))) char*)l,
        16, 0, 0);
}

// f32 -> bf16 weight conversion, vec4. grid = n/1024 blocks.
__global__ __launch_bounds__(256) void w2b_kernel(const float* __restrict__ s,
                                                  bf16* __restrict__ d)
{
    const size_t i = ((size_t)blockIdx.x * 256 + threadIdx.x) * 4;
    const float4 f = *(const float4*)(s + i);
    bf16x4 t;
    t[0] = (bf16)f.x; t[1] = (bf16)f.y; t[2] = (bf16)f.z; t[3] = (bf16)f.w;
    *(bf16x4*)(d + i) = t;
}

// ---------------------------------------------------------------------------
// 128x128-tile GEMM (2-barrier structure) — kept for small-N GEMMs.
// C(MxN) = A(MxK)bf16 @ B(NxK)bf16^T, f32 accum. EPI1 adds residual.
// ---------------------------------------------------------------------------
template <int EPI>
__global__ __launch_bounds__(256) void gemm_kernel(
    const bf16* __restrict__ A, const bf16* __restrict__ B,
    const float* __restrict__ res, float* __restrict__ Cout,
    int M, int N, int K)
{
    __shared__ bf16 As[128 * 32];
    __shared__ bf16 Bs[128 * 32];
    const int tid = threadIdx.x;
    const int wave = tid >> 6, lane = tid & 63;
    const int quad = lane >> 4, l16 = lane & 15;

    const int nby = M >> 7, nbx = N >> 7;
    const int nwg = nbx * nby;
    int bid = blockIdx.x;
    {
        const int q = nwg >> 3, r = nwg & 7;
        const int x = bid & 7, loc = bid >> 3;
        bid = (x < r ? x * (q + 1) : r * (q + 1) + (x - r) * q) + loc;
    }
    const int pg = nbx << 3;
    const int g = bid / pg, rem = bid - g * pg;
    const int by = (g << 3) + (rem & 7);
    const int bx = rem >> 3;
    const int row0 = by << 7, col0 = bx << 7;
    const int wrow = ((wave >> 1) << 6), wcol = ((wave & 1) << 6);

    f32x4 acc[4][4] = {};

    const bf16* Ag = A + (size_t)(row0 + (tid >> 2)) * K + (tid & 3) * 8;
    const bf16* Bg = B + (size_t)(col0 + (tid >> 2)) * K + (tid & 3) * 8;
    bf16* Asw = As + wave * 512;
    bf16* Bsw = Bs + wave * 512;
    const size_t K64 = (size_t)64 * K;

    for (int kb = 0; kb < K; kb += 32) {
        async_cp16(Ag + kb,        Asw);
        async_cp16(Ag + K64 + kb,  Asw + 2048);
        async_cp16(Bg + kb,        Bsw);
        async_cp16(Bg + K64 + kb,  Bsw + 2048);
        __syncthreads();
        bf16x8 af[4], bfr[4];
#pragma unroll
        for (int i = 0; i < 4; ++i)
            af[i] = *(const bf16x8*)(&As[(wrow + i * 16 + l16) * 32 + quad * 8]);
#pragma unroll
        for (int j = 0; j < 4; ++j)
            bfr[j] = *(const bf16x8*)(&Bs[(wcol + j * 16 + l16) * 32 + quad * 8]);
#pragma unroll
        for (int i = 0; i < 4; ++i)
#pragma unroll
            for (int j = 0; j < 4; ++j)
                acc[i][j] = mfma16(af[i], bfr[j], acc[i][j]);
        __syncthreads();
    }

#pragma unroll
    for (int i = 0; i < 4; ++i) {
        const int row = row0 + wrow + i * 16 + quad * 4;
#pragma unroll
        for (int j = 0; j < 4; ++j) {
            const int col = col0 + wcol + j * 16 + l16;
#pragma unroll
            for (int r = 0; r < 4; ++r) {
                const size_t idx = (size_t)(row + r) * N + col;
                float v = acc[i][j][r];
                if (EPI == 1) Cout[idx] = v + res[idx];
                else          Cout[idx] = v;
            }
        }
    }
}

// ---------------------------------------------------------------------------
// 256x256-tile GEMM, v3: 2-barrier counted-pipeline per K-tile.
// 512 threads = 8 waves (2Mx4N), per-wave 128x64, BK=64, dbuf LDS 128 KiB.
//
// Per-wave read/issue schedule (reads always issued >=1 MFMA-window ahead):
//   [prev tile pB tail] issue af0,bf0,bf1 reads (16)  <- buffer for THIS tile
//   pA: stage A[t+1]->As[n]; lgkm(4); Q00; lgkm(0); Q01; issue af1 (8); BAR1
//   pB: stage B[t+2]->Bs[c]; lgkm(0); Q10; Q11; vmcnt(4); issue next 16; BAR2
// Hazard proof (all cross-wave):
//  - stage A[t+1]->As[n]: readers of As[n] (= A[t-1]) drained by each wave's
//    lgkm at t-1 pB, all waves passed BAR2(t-1) before pA(t).
//  - stage B[t+2]->Bs[c]: readers of Bs[c] (= B[t]) drained at pA(t) lgkm
//    before Q01; all waves passed BAR1(t) before the stage.
//  - tail reads of As[n]/Bs[n]: contents guaranteed by vmcnt(4) (leaves only
//    B[t+2] outstanding); no concurrent writer (A stages target c next tile,
//    B[t+3]->Bs[n] happens after BAR1(t+1) which follows those reads' drain).
// vmcnt: stages per wave = A:4 @pA, B:4 @pB -> steady vmcnt(4); prologue
// stages A0,B0,A1,B1 (16) -> vmcnt(8) = A0,B0 landed.
// ---------------------------------------------------------------------------
template <int EPI>
__global__ __launch_bounds__(512, 2) void gemm256_kernel(
    const bf16* __restrict__ A, const bf16* __restrict__ B,
    const float* __restrict__ res, float* __restrict__ Cout,
    int M, int N, int K)
{
    __shared__ bf16 As[2][2][128][64];
    __shared__ bf16 Bs[2][2][128][64];
    const int tid = threadIdx.x;
    const int wid = tid >> 6, lane = tid & 63;
    const int quad = lane >> 4, l16 = lane & 15;
    const int wm = wid >> 2, wn = wid & 3;
    const int xsw = l16 & 7;
    const int bofs = (wn & 1) * 64;

    const int nby = M >> 8, nbx = N >> 8;
    const int nwg = nbx * nby;
    int bid = blockIdx.x;
    {
        const int q = nwg >> 3, r = nwg & 7;
        const int x = bid & 7, loc = bid >> 3;
        bid = (x < r ? x * (q + 1) : r * (q + 1) + (x - r) * q) + loc;
    }
    const int pg = nbx << 3;
    const int g = bid / pg, rem = bid - g * pg;
    const int by = (g << 3) + (rem & 7);
    const int bx = rem >> 3;
    const int row0 = by << 8, col0 = bx << 8;

    const int srow = tid >> 3;
    const int scol = ((tid & 7) ^ ((tid >> 3) & 7)) * 8;
    const bf16* Abase = A + (size_t)(row0 + srow) * K + scol;
    const bf16* Bbase = B + (size_t)(col0 + srow) * K + scol;
    const size_t K64 = (size_t)K * 64;
    const size_t K128 = (size_t)K * 128;

    f32x4 acc[8][4] = {};
    bf16x8 af[8], bf0[4], bf1[4];

#define STG_A(BUF, HH, KB) do { \
    const bf16* _g = Abase + (size_t)(HH) * K128 + (KB); \
    bf16* _l = &As[BUF][HH][0][0] + wid * 512; \
    async_cp16(_g, _l); \
    async_cp16(_g + K64, _l + 4096); } while (0)
#define STG_B(BUF, HH, KB) do { \
    const bf16* _g = Bbase + (size_t)(HH) * K128 + (KB); \
    bf16* _l = &Bs[BUF][HH][0][0] + wid * 512; \
    async_cp16(_g, _l); \
    async_cp16(_g + K64, _l + 4096); } while (0)

#define RD_A(BUF, RH) do { \
    const bf16 (*Ah_)[64] = As[BUF][wm]; \
    _Pragma("unroll") for (int f = 0; f < 4; ++f) { \
        af[f*2+0] = *(const bf16x8*)(&Ah_[(RH)*64 + f*16 + l16][(quad ^ xsw) * 8]); \
        af[f*2+1] = *(const bf16x8*)(&Ah_[(RH)*64 + f*16 + l16][((4 + quad) ^ xsw) * 8]); } } while (0)

#define RD_B(BUF, CH, BF) do { \
    const bf16 (*Bh_)[64] = Bs[BUF][wn >> 1]; \
    _Pragma("unroll") for (int f = 0; f < 2; ++f) { \
        BF[f*2+0] = *(const bf16x8*)(&Bh_[bofs + (CH)*32 + f*16 + l16][(quad ^ xsw) * 8]); \
        BF[f*2+1] = *(const bf16x8*)(&Bh_[bofs + (CH)*32 + f*16 + l16][((4 + quad) ^ xsw) * 8]); } } while (0)

#define MFMA_Q(RH, CH, BF) do { \
    _Pragma("unroll") for (int f = 0; f < 4; ++f) \
    _Pragma("unroll") for (int f2 = 0; f2 < 2; ++f2) { \
        acc[(RH)*4+f][(CH)*2+f2] = mfma16(af[f*2+0], BF[f2*2+0], acc[(RH)*4+f][(CH)*2+f2]); \
        acc[(RH)*4+f][(CH)*2+f2] = mfma16(af[f*2+1], BF[f2*2+1], acc[(RH)*4+f][(CH)*2+f2]); } } while (0)

    const int NT = K >> 6;
    // prologue: stage A0,B0 (and A1,B1); wait for tile 0; issue tile-0 reads
    STG_A(0, 0, 0); STG_A(0, 1, 0); STG_B(0, 0, 0); STG_B(0, 1, 0);
    if (NT > 1) {
        STG_A(1, 0, 64); STG_A(1, 1, 64); STG_B(1, 0, 64); STG_B(1, 1, 64);
        asm volatile("s_waitcnt vmcnt(8)" ::: "memory");
    } else {
        asm volatile("s_waitcnt vmcnt(0)" ::: "memory");
    }
    __builtin_amdgcn_sched_barrier(0);
    __builtin_amdgcn_s_barrier();
    RD_A(0, 0); RD_B(0, 0, bf0); RD_B(0, 1, bf1);
    __builtin_amdgcn_sched_barrier(0);

    for (int t = 0; t < NT; ++t) {
        const int c = t & 1, n = c ^ 1;
        const int kb1 = (t + 1) << 6, kb2 = (t + 2) << 6;
        // ---------------- phase A ----------------
        if (t >= 1 && t + 1 < NT) { STG_A(n, 0, kb1); STG_A(n, 1, kb1); }
        asm volatile("s_waitcnt lgkmcnt(4)" ::: "memory");   // af0+bf0 ready
        __builtin_amdgcn_sched_barrier(0);
        __builtin_amdgcn_s_setprio(1);
        MFMA_Q(0, 0, bf0);
        __builtin_amdgcn_s_setprio(0);
        asm volatile("s_waitcnt lgkmcnt(0)" ::: "memory");   // bf1 ready
        __builtin_amdgcn_sched_barrier(0);
        __builtin_amdgcn_s_setprio(1);
        MFMA_Q(0, 1, bf1);
        __builtin_amdgcn_s_setprio(0);
        RD_A(c, 1);                                          // af1: hides under Q01 drain
        __builtin_amdgcn_sched_barrier(0);
        __builtin_amdgcn_s_barrier();                        // BAR1
        // ---------------- phase B ----------------
        if (t + 2 < NT) { STG_B(c, 0, kb2); STG_B(c, 1, kb2); }
        asm volatile("s_waitcnt lgkmcnt(0)" ::: "memory");   // af1 ready
        __builtin_amdgcn_sched_barrier(0);
        __builtin_amdgcn_s_setprio(1);
        MFMA_Q(1, 0, bf0);
        MFMA_Q(1, 1, bf1);
        __builtin_amdgcn_s_setprio(0);
        if (t + 1 < NT) {
            if (t + 2 < NT) { asm volatile("s_waitcnt vmcnt(4)" ::: "memory"); }
            else            { asm volatile("s_waitcnt vmcnt(0)" ::: "memory"); }
            __builtin_amdgcn_sched_barrier(0);
            RD_A(n, 0); RD_B(n, 0, bf0); RD_B(n, 1, bf1);    // next tile's operands
            __builtin_amdgcn_sched_barrier(0);
        }
        __builtin_amdgcn_s_barrier();                        // BAR2
    }
#undef STG_A
#undef STG_B
#undef RD_A
#undef RD_B
#undef MFMA_Q

#pragma unroll
    for (int fr = 0; fr < 8; ++fr) {
        const int row = row0 + wm * 128 + fr * 16 + quad * 4;
#pragma unroll
        for (int fc = 0; fc < 4; ++fc) {
            const int col = col0 + wn * 64 + fc * 16 + l16;
#pragma unroll
            for (int r = 0; r < 4; ++r) {
                const size_t idx = (size_t)(row + r) * N + col;
                float v = acc[fr][fc][r];
                if (EPI == 1) Cout[idx] = v + res[idx];
                else          Cout[idx] = v;
            }
        }
    }
}

// ---------------------------------------------------------------------------
// prenorm+concat: xcat[row,0:1024]=rmsnorm(emb), [1024:2048]=rmsnorm(hid)
// ---------------------------------------------------------------------------
__global__ __launch_bounds__(256) void prenorm_kernel(
    const float* __restrict__ emb, const float* __restrict__ hid,
    const float* __restrict__ we, const float* __restrict__ wh,
    bf16* __restrict__ xcat)
{
    const int rr = blockIdx.x * 4 + (threadIdx.x >> 6);
    const int lane = threadIdx.x & 63;
    const int half = rr & 1, row = rr >> 1;
    const float* x = (half ? hid : emb) + (size_t)row * 1024;
    const float* w = half ? wh : we;
    float4 v[4]; float ss = 0.f;
#pragma unroll
    for (int j = 0; j < 4; ++j) {
        v[j] = *(const float4*)(x + (size_t)(lane + 64 * j) * 4);
        ss += v[j].x * v[j].x + v[j].y * v[j].y + v[j].z * v[j].z + v[j].w * v[j].w;
    }
#pragma unroll
    for (int m = 32; m; m >>= 1) ss += __shfl_xor(ss, m, 64);
    const float rms = rsqrtf(ss * (1.f / 1024.f) + 1e-6f);
    bf16* o = xcat + (size_t)row * 2048 + half * 1024;
#pragma unroll
    for (int j = 0; j < 4; ++j) {
        const int d = (lane + 64 * j) * 4;
        float4 wv = *(const float4*)(w + d);
        bf16x4 t;
        t[0] = (bf16)(v[j].x * rms * wv.x);
        t[1] = (bf16)(v[j].y * rms * wv.y);
        t[2] = (bf16)(v[j].z * rms * wv.z);
        t[3] = (bf16)(v[j].w * rms * wv.w);
        *(bf16x4*)(o + d) = t;
    }
}

// rmsnorm over H=1024, f32 in -> bf16 out, one wave per row
__global__ __launch_bounds__(256) void rmsnorm_kernel(
    const float* __restrict__ xin, const float* __restrict__ w, bf16* __restrict__ out)
{
    const int row = blockIdx.x * 4 + (threadIdx.x >> 6);
    const int lane = threadIdx.x & 63;
    const float* x = xin + (size_t)row * 1024;
    float4 v[4]; float ss = 0.f;
#pragma unroll
    for (int j = 0; j < 4; ++j) {
        v[j] = *(const float4*)(x + (size_t)(lane + 64 * j) * 4);
        ss += v[j].x * v[j].x + v[j].y * v[j].y + v[j].z * v[j].z + v[j].w * v[j].w;
    }
#pragma unroll
    for (int m = 32; m; m >>= 1) ss += __shfl_xor(ss, m, 64);
    const float rms = rsqrtf(ss * (1.f / 1024.f) + 1e-6f);
    bf16* o = out + (size_t)row * 1024;
#pragma unroll
    for (int j = 0; j < 4; ++j) {
        const int d = (lane + 64 * j) * 4;
        float4 wv = *(const float4*)(w + d);
        bf16x4 t;
        t[0] = (bf16)(v[j].x * rms * wv.x);
        t[1] = (bf16)(v[j].y * rms * wv.y);
        t[2] = (bf16)(v[j].z * rms * wv.z);
        t[3] = (bf16)(v[j].w * rms * wv.w);
        *(bf16x4*)(o + d) = t;
    }
}

// ---------------------------------------------------------------------------
// q prep: rmsnorm(D=256) -> rope(first 64, interleaved) -> *1/16 -> bf16
// ---------------------------------------------------------------------------
__global__ __launch_bounds__(256) void qprep_kernel(
    const float* __restrict__ qg, const float* __restrict__ qn_w, bf16* __restrict__ qa)
{
    const int row = blockIdx.x * 4 + (threadIdx.x >> 6);  // (b*L+l)*8+h
    const int lane = threadIdx.x & 63;
    const int h = row & 7, bl = row >> 3;
    const int l = bl & 2047, b = bl >> 11;
    const float* x = qg + (size_t)row * 512;
    float v[4]; float ss = 0.f;
#pragma unroll
    for (int j = 0; j < 4; ++j) { v[j] = x[lane + 64 * j]; ss += v[j] * v[j]; }
#pragma unroll
    for (int m = 32; m; m >>= 1) ss += __shfl_xor(ss, m, 64);
    const float rms = rsqrtf(ss * (1.f / 256.f) + 1e-6f);
    float y[4];
#pragma unroll
    for (int j = 0; j < 4; ++j) y[j] = v[j] * rms * qn_w[lane + 64 * j];
    {
        const float p = __shfl_xor(y[0], 1, 64);
        const int i2 = lane >> 1;
        const float inv = powf(1e7f, -(float)(2 * i2) * (1.f / 64.f));
        const float ang = (float)l * inv;
        const float c = cosf(ang), s = sinf(ang);
        y[0] = (lane & 1) ? (p * s + y[0] * c) : (y[0] * c - p * s);
    }
    bf16* o = qa + ((size_t)((b * 8 + h) * 2048 + l)) * 256;
#pragma unroll
    for (int j = 0; j < 4; ++j) o[lane + 64 * j] = (bf16)(y[j] * 0.0625f);
}

// k prep: same minus scale; (B,L,NKV,D) f32 -> (B,NKV,L,D) bf16
__global__ __launch_bounds__(256) void kprep_kernel(
    const float* __restrict__ kf, const float* __restrict__ kn_w, bf16* __restrict__ ka)
{
    const int row = blockIdx.x * 4 + (threadIdx.x >> 6);  // (b*L+l)*2+kv
    const int lane = threadIdx.x & 63;
    const int kv = row & 1, bl = row >> 1;
    const int l = bl & 2047, b = bl >> 11;
    const float* x = kf + (size_t)row * 256;
    float v[4]; float ss = 0.f;
#pragma unroll
    for (int j = 0; j < 4; ++j) { v[j] = x[lane + 64 * j]; ss += v[j] * v[j]; }
#pragma unroll
    for (int m = 32; m; m >>= 1) ss += __shfl_xor(ss, m, 64);
    const float rms = rsqrtf(ss * (1.f / 256.f) + 1e-6f);
    float y[4];
#pragma unroll
    for (int j = 0; j < 4; ++j) y[j] = v[j] * rms * kn_w[lane + 64 * j];
    {
        const float p = __shfl_xor(y[0], 1, 64);
        const int i2 = lane >> 1;
        const float inv = powf(1e7f, -(float)(2 * i2) * (1.f / 64.f));
        const float ang = (float)l * inv;
        const float c = cosf(ang), s = sinf(ang);
        y[0] = (lane & 1) ? (p * s + y[0] * c) : (y[0] * c - p * s);
    }
    bf16* o = ka + ((size_t)((b * 2 + kv) * 2048 + l)) * 256;
#pragma unroll
    for (int j = 0; j < 4; ++j) o[lane + 64 * j] = (bf16)y[j];
}

// v prep: (B,L,NKV,D) f32 -> (B,NKV,D,L) bf16 via LDS 64x64 tile transpose.
__global__ __launch_bounds__(256) void vprep_kernel(const float* __restrict__ vf,
                                                    bf16* __restrict__ vt)
{
    __shared__ float t[64][65];
    const int l0 = blockIdx.x << 6;
    const int d0 = blockIdx.y << 6;
    const int b = blockIdx.z >> 1, kv = blockIdx.z & 1;
    const int tx = threadIdx.x & 63, ty = threadIdx.x >> 6;
    const float* src = vf + ((size_t)b * 4096 + kv) * 256;
#pragma unroll
    for (int j = 0; j < 16; ++j) {
        const int l = ty + j * 4;
        t[l][tx] = src[(size_t)(l0 + l) * 512 + d0 + tx];
    }
    __syncthreads();
    bf16* dst = vt + (size_t)(b * 2 + kv) * 256 * 2048;
#pragma unroll
    for (int j = 0; j < 16; ++j) {
        const int d = ty + j * 4;
        dst[(size_t)(d0 + d) * 2048 + l0 + tx] = (bf16)t[tx][d];
    }
}

// ---------------------------------------------------------------------------
// flash attention, balanced (R3 form): 1 block = (b, h, q-tile pair {j,31-j}).
// Every block does exactly 66 kv-tiles -> uniform duration, full residency.
// ---------------------------------------------------------------------------
__global__ __launch_bounds__(256) void attn_kernel(
    const bf16* __restrict__ qa, const bf16* __restrict__ ka,
    const bf16* __restrict__ vt, float* __restrict__ of)
{
    __shared__ bf16 Ks[32 * 264];
    __shared__ bf16 Vt[256 * 40];
    __shared__ bf16 Pw[4 * 16 * 40];
    const int tid = threadIdx.x;
    const int wave = tid >> 6, lane = tid & 63;
    const int quad = lane >> 4, l16 = lane & 15;
    const int bid = blockIdx.x;
    const int j = bid & 15, h = (bid >> 4) & 7, b = bid >> 7;
    const int kvh = h >> 2;
    const bf16* qptr = qa + ((size_t)(b * 8 + h)) * 2048 * 256;
    const bf16* kptr = ka + ((size_t)(b * 2 + kvh)) * 2048 * 256;
    const bf16* vptr = vt + ((size_t)(b * 2 + kvh)) * 256 * 2048;
    float* optr = of + ((size_t)(b * 8 + h)) * 2048 * 256;

    for (int s = 0; s < 2; ++s) {
        const int qt = s ? (31 - j) : j;
        const int qbase = qt * 64 + wave * 16;

        bf16x8 qf[8];
#pragma unroll
        for (int db = 0; db < 8; ++db)
            qf[db] = *(const bf16x8*)(qptr + (size_t)(qbase + l16) * 256 + db * 32 + quad * 8);

        f32x4 o_acc[16] = {};
        float m_i[4], l_i[4];
#pragma unroll
        for (int r = 0; r < 4; ++r) { m_i[r] = -1e30f; l_i[r] = 0.f; }

        const int ntiles = qt * 2 + 2;
        for (int kt = 0; kt < ntiles; ++kt) {
            const int kvs = kt * 32;
#pragma unroll
            for (int c = 0; c < 4; ++c) {
                const int idx = tid + c * 256;
                const int kr = idx >> 5, kc = (idx & 31) * 8;
                *(bf16x8*)(&Ks[kr * 264 + kc]) = *(const bf16x8*)(kptr + (size_t)(kvs + kr) * 256 + kc);
                const int vd = idx >> 2, vc = (idx & 3) * 8;
                *(bf16x8*)(&Vt[vd * 40 + vc]) = *(const bf16x8*)(vptr + (size_t)vd * 2048 + kvs + vc);
            }
            __syncthreads();

            f32x4 s0 = {}, s1 = {};
#pragma unroll
            for (int db = 0; db < 8; ++db) {
                bf16x8 k0 = *(const bf16x8*)(&Ks[l16 * 264 + db * 32 + quad * 8]);
                bf16x8 k1 = *(const bf16x8*)(&Ks[(16 + l16) * 264 + db * 32 + quad * 8]);
                s0 = mfma16(qf[db], k0, s0);
                s1 = mfma16(qf[db], k1, s1);
            }

            float alpha[4], p0v[4], p1v[4];
#pragma unroll
            for (int r = 0; r < 4; ++r) {
                const int qrow = qbase + quad * 4 + r;
                float a0 = (kvs + l16 > qrow) ? -1e30f : s0[r];
                float a1 = (kvs + 16 + l16 > qrow) ? -1e30f : s1[r];
                float mx = fmaxf(a0, a1);
#pragma unroll
                for (int m = 8; m; m >>= 1) mx = fmaxf(mx, __shfl_xor(mx, m, 64));
                const float mnew = fmaxf(m_i[r], mx);
                const float a = __expf(m_i[r] - mnew);
                const float p0 = __expf(a0 - mnew);
                const float p1 = __expf(a1 - mnew);
                float ps = p0 + p1;
#pragma unroll
                for (int m = 8; m; m >>= 1) ps += __shfl_xor(ps, m, 64);
                l_i[r] = l_i[r] * a + ps;
                m_i[r] = mnew;
                alpha[r] = a; p0v[r] = p0; p1v[r] = p1;
            }
#pragma unroll
            for (int t = 0; t < 16; ++t) {
                f32x4 o = o_acc[t];
                o[0] *= alpha[0]; o[1] *= alpha[1]; o[2] *= alpha[2]; o[3] *= alpha[3];
                o_acc[t] = o;
            }
            bf16* pw = &Pw[wave * 16 * 40];
#pragma unroll
            for (int r = 0; r < 4; ++r) {
                pw[(quad * 4 + r) * 40 + l16]      = (bf16)p0v[r];
                pw[(quad * 4 + r) * 40 + 16 + l16] = (bf16)p1v[r];
            }
            __syncthreads();
            const bf16x8 pa = *(const bf16x8*)(&pw[l16 * 40 + quad * 8]);
#pragma unroll
            for (int t = 0; t < 16; ++t) {
                bf16x8 vfr = *(const bf16x8*)(&Vt[(t * 16 + l16) * 40 + quad * 8]);
                o_acc[t] = mfma16(pa, vfr, o_acc[t]);
            }
            __syncthreads();
        }

#pragma unroll
        for (int r = 0; r < 4; ++r) {
            const float inv = 1.f / l_i[r];
            const int row = qbase + quad * 4 + r;
#pragma unroll
            for (int t = 0; t < 16; ++t)
                optr[(size_t)row * 256 + t * 16 + l16] = o_acc[t][r] * inv;
        }
    }
}

// gated output: ag[(b,l,h*256+d)] = of[(b,h,l,d)] * sigmoid(qg gate)
__global__ void gating_kernel(const float* __restrict__ of, const float* __restrict__ qg,
                              bf16* __restrict__ ag)
{
    const size_t i = (size_t)blockIdx.x * 256 + threadIdx.x;
    const int d = (int)(i & 255);
    const int h = (int)((i >> 8) & 7);
    const size_t bl = i >> 11;
    const float o = of[((size_t)((bl >> 11) * 8 + h) * 2048 + (bl & 2047)) * 256 + d];
    const float g = qg[(bl * 8 + h) * 512 + 256 + d];
    ag[i] = (bf16)(o * (1.f / (1.f + __expf(-g))));
}

// h = bf16(silu(g) * u)
__global__ void silu_kernel(const float* __restrict__ g, const float* __restrict__ u,
                            bf16* __restrict__ h)
{
    const size_t i = ((size_t)blockIdx.x * 256 + threadIdx.x) * 4;
    const float4 gv = *(const float4*)(g + i);
    const float4 uv = *(const float4*)(u + i);
    bf16x4 t;
    t[0] = (bf16)(gv.x * (1.f / (1.f + __expf(-gv.x))) * uv.x);
    t[1] = (bf16)(gv.y * (1.f / (1.f + __expf(-gv.y))) * uv.y);
    t[2] = (bf16)(gv.z * (1.f / (1.f + __expf(-gv.z))) * uv.z);
    t[3] = (bf16)(gv.w * (1.f / (1.f + __expf(-gv.w))) * uv.w);
    *(bf16x4*)(h + i) = t;
}

// ---------------------------------------------------------------------------
extern "C" void kernel_launch(void* const* d_in, const int* in_sizes, int n_in,
                              void* d_out, int out_size, void* d_ws, size_t ws_size,
                              hipStream_t stream)
{
    const float* emb       = (const float*)d_in[0];
    const float* hid       = (const float*)d_in[1];
    const float* pre_emb_w = (const float*)d_in[2];
    const float* pre_hid_w = (const float*)d_in[3];
    const float* fc_w      = (const float*)d_in[4];
    const float* in_ln_w   = (const float*)d_in[5];
    const float* q_w       = (const float*)d_in[6];
    const float* k_w       = (const float*)d_in[7];
    const float* v_w       = (const float*)d_in[8];
    const float* o_w       = (const float*)d_in[9];
    const float* qn_w      = (const float*)d_in[10];
    const float* kn_w      = (const float*)d_in[11];
    const float* post_ln_w = (const float*)d_in[12];
    const float* gate_w    = (const float*)d_in[13];
    const float* up_w      = (const float*)d_in[14];
    const float* down_w    = (const float*)d_in[15];
    const float* norm_w    = (const float*)d_in[16];
    const float* lm_w      = (const float*)d_in[17];
    float* out = (float*)d_out;
    char* ws = (char*)d_ws;

    // workspace layout (lifetime-overlapped), total 360 MiB (unchanged)
    float* xres = (float*)(ws + 0);                 // 32 MiB, residual (in-place)
    bf16*  xln  = (bf16*)(ws + 33554432);           // 16 MiB, reused 3x
    char*  C    = ws + 50331648;                    // 128 MiB: qg then gate_f32 (+ wb slots)
    char*  D    = ws + 184549376;                   // 128 MiB: xcat/kf/vf/of then up_f32
    char*  E    = ws + 318767104;                   // 56 MiB: qa/ka/va then ag then h
    float* qg   = (float*)C;
    float* gf   = (float*)C;
    bf16*  xcat = (bf16*)D;
    float* kf   = (float*)(D + 33554432);
    float* vf   = (float*)(D + 50331648);
    float* of   = (float*)(D + 67108864);
    float* uf   = (float*)D;
    bf16*  qa   = (bf16*)E;
    bf16*  ka   = (bf16*)(E + 33554432);
    bf16*  va   = (bf16*)(E + 41943040);
    bf16*  ag   = (bf16*)E;
    bf16*  hb   = (bf16*)E;
    // bf16 weight scratch slots (placed in regions dead at time of use)
    bf16*  wbC  = (bf16*)C;                  // fc(4M), o(4M), down(7M), lm(32M)
    bf16*  wbD  = (bf16*)D;                  // q(8M), k(1M), v(1M)
    bf16*  wbDt = (bf16*)(D + 117440512);    // gate(7M), up(7M) — above uf

    prenorm_kernel<<<4096, 256, 0, stream>>>(emb, hid, pre_emb_w, pre_hid_w, xcat);

    w2b_kernel<<<2048, 256, 0, stream>>>(fc_w, wbC);                       // 1024x2048
    gemm_kernel<0><<<512, 256, 0, stream>>>(xcat, wbC, nullptr, xres, 8192, 1024, 2048);
    rmsnorm_kernel<<<2048, 256, 0, stream>>>(xres, in_ln_w, xln);

    w2b_kernel<<<4096, 256, 0, stream>>>(q_w, wbD);                        // 4096x1024
    gemm256_kernel<0><<<512, 512, 0, stream>>>(xln, wbD, nullptr, qg, 8192, 4096, 1024);
    w2b_kernel<<<512, 256, 0, stream>>>(k_w, wbD);                         // 512x1024
    gemm_kernel<0><<<256, 256, 0, stream>>>(xln, wbD, nullptr, kf, 8192, 512, 1024);
    w2b_kernel<<<512, 256, 0, stream>>>(v_w, wbD);
    gemm_kernel<0><<<256, 256, 0, stream>>>(xln, wbD, nullptr, vf, 8192, 512, 1024);

    qprep_kernel<<<16384, 256, 0, stream>>>(qg, qn_w, qa);
    kprep_kernel<<<4096, 256, 0, stream>>>(kf, kn_w, ka);
    vprep_kernel<<<dim3(32, 4, 8), 256, 0, stream>>>(vf, va);
    attn_kernel<<<512, 256, 0, stream>>>(qa, ka, va, of);
    gating_kernel<<<65536, 256, 0, stream>>>(of, qg, ag);

    w2b_kernel<<<2048, 256, 0, stream>>>(o_w, wbC);                        // 1024x2048
    gemm_kernel<1><<<512, 256, 0, stream>>>(ag, wbC, xres, xres, 8192, 1024, 2048);
    rmsnorm_kernel<<<2048, 256, 0, stream>>>(xres, post_ln_w, xln);

    w2b_kernel<<<3584, 256, 0, stream>>>(gate_w, wbDt);                    // 3584x1024
    gemm256_kernel<0><<<448, 512, 0, stream>>>(xln, wbDt, nullptr, gf, 8192, 3584, 1024);
    w2b_kernel<<<3584, 256, 0, stream>>>(up_w, wbDt);
    gemm256_kernel<0><<<448, 512, 0, stream>>>(xln, wbDt, nullptr, uf, 8192, 3584, 1024);
    silu_kernel<<<28672, 256, 0, stream>>>(gf, uf, hb);

    w2b_kernel<<<3584, 256, 0, stream>>>(down_w, wbC);                     // 1024x3584
    gemm_kernel<1><<<512, 256, 0, stream>>>(hb, wbC, xres, xres, 8192, 1024, 3584);
    rmsnorm_kernel<<<2048, 256, 0, stream>>>(xres, norm_w, xln);

    w2b_kernel<<<16384, 256, 0, stream>>>(lm_w, wbC);                      // 16384x1024
    gemm256_kernel<0><<<2048, 512, 0, stream>>>(xln, wbC, nullptr, out, 8192, 16384, 1024);
}

// Round 6
// 1786.776 us; speedup vs baseline: 1.0749x; 1.0396x over previous
//
#include <hip/hip_runtime.h>

typedef __bf16 bf16;
typedef __bf16 bf16x8 __attribute__((ext_vector_type(8)));
typedef __bf16 bf16x4 __attribute__((ext_vector_type(4)));
typedef float f32x4 __attribute__((ext_vector_type(4)));

__device__ inline f32x4 mfma16(bf16x8 a, bf16x8 b, f32x4 c) {
    return __builtin_amdgcn_mfma_f32_16x16x32_bf16(a, b, c, 0, 0, 0);
}

// async global->LDS, 16B per lane. LDS dest is wave-uniform base + lane*16.
__device__ __forceinline__ void async_cp16(const void* g, void* l) {
    __builtin_amdgcn_global_load_lds(
        (__attribute__((address_space(1))) char*)g,
        (__attribute__((address_space(3))) char*)l,
        16, 0, 0);
}

// f32 -> bf16 weight conversion, vec4. grid = n/1024 blocks.
__global__ __launch_bounds__(256) void w2b_kernel(const float* __restrict__ s,
                                                  bf16* __restrict__ d)
{
    const size_t i = ((size_t)blockIdx.x * 256 + threadIdx.x) * 4;
    const float4 f = *(const float4*)(s + i);
    bf16x4 t;
    t[0] = (bf16)f.x; t[1] = (bf16)f.y; t[2] = (bf16)f.z; t[3] = (bf16)f.w;
    *(bf16x4*)(d + i) = t;
}

// ---------------------------------------------------------------------------
// 128x128-tile GEMM (2-barrier structure) — kept for small-N GEMMs.
// C(MxN) = A(MxK)bf16 @ B(NxK)bf16^T, f32 accum. EPI1 adds residual.
// ---------------------------------------------------------------------------
template <int EPI>
__global__ __launch_bounds__(256) void gemm_kernel(
    const bf16* __restrict__ A, const bf16* __restrict__ B,
    const float* __restrict__ res, float* __restrict__ Cout,
    int M, int N, int K)
{
    __shared__ bf16 As[128 * 32];
    __shared__ bf16 Bs[128 * 32];
    const int tid = threadIdx.x;
    const int wave = tid >> 6, lane = tid & 63;
    const int quad = lane >> 4, l16 = lane & 15;

    const int nby = M >> 7, nbx = N >> 7;
    const int nwg = nbx * nby;
    int bid = blockIdx.x;
    {
        const int q = nwg >> 3, r = nwg & 7;
        const int x = bid & 7, loc = bid >> 3;
        bid = (x < r ? x * (q + 1) : r * (q + 1) + (x - r) * q) + loc;
    }
    const int pg = nbx << 3;
    const int g = bid / pg, rem = bid - g * pg;
    const int by = (g << 3) + (rem & 7);
    const int bx = rem >> 3;
    const int row0 = by << 7, col0 = bx << 7;
    const int wrow = ((wave >> 1) << 6), wcol = ((wave & 1) << 6);

    f32x4 acc[4][4] = {};

    const bf16* Ag = A + (size_t)(row0 + (tid >> 2)) * K + (tid & 3) * 8;
    const bf16* Bg = B + (size_t)(col0 + (tid >> 2)) * K + (tid & 3) * 8;
    bf16* Asw = As + wave * 512;
    bf16* Bsw = Bs + wave * 512;
    const size_t K64 = (size_t)64 * K;

    for (int kb = 0; kb < K; kb += 32) {
        async_cp16(Ag + kb,        Asw);
        async_cp16(Ag + K64 + kb,  Asw + 2048);
        async_cp16(Bg + kb,        Bsw);
        async_cp16(Bg + K64 + kb,  Bsw + 2048);
        __syncthreads();
        bf16x8 af[4], bfr[4];
#pragma unroll
        for (int i = 0; i < 4; ++i)
            af[i] = *(const bf16x8*)(&As[(wrow + i * 16 + l16) * 32 + quad * 8]);
#pragma unroll
        for (int j = 0; j < 4; ++j)
            bfr[j] = *(const bf16x8*)(&Bs[(wcol + j * 16 + l16) * 32 + quad * 8]);
#pragma unroll
        for (int i = 0; i < 4; ++i)
#pragma unroll
            for (int j = 0; j < 4; ++j)
                acc[i][j] = mfma16(af[i], bfr[j], acc[i][j]);
        __syncthreads();
    }

#pragma unroll
    for (int i = 0; i < 4; ++i) {
        const int row = row0 + wrow + i * 16 + quad * 4;
#pragma unroll
        for (int j = 0; j < 4; ++j) {
            const int col = col0 + wcol + j * 16 + l16;
#pragma unroll
            for (int r = 0; r < 4; ++r) {
                const size_t idx = (size_t)(row + r) * N + col;
                float v = acc[i][j][r];
                if (EPI == 1) Cout[idx] = v + res[idx];
                else          Cout[idx] = v;
            }
        }
    }
}

// ---------------------------------------------------------------------------
// 256x256-tile GEMM, v3: 2-barrier counted-pipeline per K-tile (see R4 notes).
// EPI: 0 = f32 out; 1 = f32 out + residual; 2 = hout = bf16(silu(res)*acc)
// (fused SiLU-mul epilogue for the up-projection; res carries the gate GEMM
//  output, hout the bf16 hidden buffer).
// ---------------------------------------------------------------------------
template <int EPI>
__global__ __launch_bounds__(512, 2) void gemm256_kernel(
    const bf16* __restrict__ A, const bf16* __restrict__ B,
    const float* __restrict__ res, float* __restrict__ Cout,
    bf16* __restrict__ hout, int M, int N, int K)
{
    __shared__ bf16 As[2][2][128][64];
    __shared__ bf16 Bs[2][2][128][64];
    const int tid = threadIdx.x;
    const int wid = tid >> 6, lane = tid & 63;
    const int quad = lane >> 4, l16 = lane & 15;
    const int wm = wid >> 2, wn = wid & 3;
    const int xsw = l16 & 7;
    const int bofs = (wn & 1) * 64;

    const int nby = M >> 8, nbx = N >> 8;
    const int nwg = nbx * nby;
    int bid = blockIdx.x;
    {
        const int q = nwg >> 3, r = nwg & 7;
        const int x = bid & 7, loc = bid >> 3;
        bid = (x < r ? x * (q + 1) : r * (q + 1) + (x - r) * q) + loc;
    }
    const int pg = nbx << 3;
    const int g = bid / pg, rem = bid - g * pg;
    const int by = (g << 3) + (rem & 7);
    const int bx = rem >> 3;
    const int row0 = by << 8, col0 = bx << 8;

    const int srow = tid >> 3;
    const int scol = ((tid & 7) ^ ((tid >> 3) & 7)) * 8;
    const bf16* Abase = A + (size_t)(row0 + srow) * K + scol;
    const bf16* Bbase = B + (size_t)(col0 + srow) * K + scol;
    const size_t K64 = (size_t)K * 64;
    const size_t K128 = (size_t)K * 128;

    f32x4 acc[8][4] = {};
    bf16x8 af[8], bf0[4], bf1[4];

#define STG_A(BUF, HH, KB) do { \
    const bf16* _g = Abase + (size_t)(HH) * K128 + (KB); \
    bf16* _l = &As[BUF][HH][0][0] + wid * 512; \
    async_cp16(_g, _l); \
    async_cp16(_g + K64, _l + 4096); } while (0)
#define STG_B(BUF, HH, KB) do { \
    const bf16* _g = Bbase + (size_t)(HH) * K128 + (KB); \
    bf16* _l = &Bs[BUF][HH][0][0] + wid * 512; \
    async_cp16(_g, _l); \
    async_cp16(_g + K64, _l + 4096); } while (0)

#define RD_A(BUF, RH) do { \
    const bf16 (*Ah_)[64] = As[BUF][wm]; \
    _Pragma("unroll") for (int f = 0; f < 4; ++f) { \
        af[f*2+0] = *(const bf16x8*)(&Ah_[(RH)*64 + f*16 + l16][(quad ^ xsw) * 8]); \
        af[f*2+1] = *(const bf16x8*)(&Ah_[(RH)*64 + f*16 + l16][((4 + quad) ^ xsw) * 8]); } } while (0)

#define RD_B(BUF, CH, BF) do { \
    const bf16 (*Bh_)[64] = Bs[BUF][wn >> 1]; \
    _Pragma("unroll") for (int f = 0; f < 2; ++f) { \
        BF[f*2+0] = *(const bf16x8*)(&Bh_[bofs + (CH)*32 + f*16 + l16][(quad ^ xsw) * 8]); \
        BF[f*2+1] = *(const bf16x8*)(&Bh_[bofs + (CH)*32 + f*16 + l16][((4 + quad) ^ xsw) * 8]); } } while (0)

#define MFMA_Q(RH, CH, BF) do { \
    _Pragma("unroll") for (int f = 0; f < 4; ++f) \
    _Pragma("unroll") for (int f2 = 0; f2 < 2; ++f2) { \
        acc[(RH)*4+f][(CH)*2+f2] = mfma16(af[f*2+0], BF[f2*2+0], acc[(RH)*4+f][(CH)*2+f2]); \
        acc[(RH)*4+f][(CH)*2+f2] = mfma16(af[f*2+1], BF[f2*2+1], acc[(RH)*4+f][(CH)*2+f2]); } } while (0)

    const int NT = K >> 6;
    STG_A(0, 0, 0); STG_A(0, 1, 0); STG_B(0, 0, 0); STG_B(0, 1, 0);
    if (NT > 1) {
        STG_A(1, 0, 64); STG_A(1, 1, 64); STG_B(1, 0, 64); STG_B(1, 1, 64);
        asm volatile("s_waitcnt vmcnt(8)" ::: "memory");
    } else {
        asm volatile("s_waitcnt vmcnt(0)" ::: "memory");
    }
    __builtin_amdgcn_sched_barrier(0);
    __builtin_amdgcn_s_barrier();
    RD_A(0, 0); RD_B(0, 0, bf0); RD_B(0, 1, bf1);
    __builtin_amdgcn_sched_barrier(0);

    for (int t = 0; t < NT; ++t) {
        const int c = t & 1, n = c ^ 1;
        const int kb1 = (t + 1) << 6, kb2 = (t + 2) << 6;
        // ---------------- phase A ----------------
        if (t >= 1 && t + 1 < NT) { STG_A(n, 0, kb1); STG_A(n, 1, kb1); }
        asm volatile("s_waitcnt lgkmcnt(4)" ::: "memory");   // af0+bf0 ready
        __builtin_amdgcn_sched_barrier(0);
        __builtin_amdgcn_s_setprio(1);
        MFMA_Q(0, 0, bf0);
        __builtin_amdgcn_s_setprio(0);
        asm volatile("s_waitcnt lgkmcnt(0)" ::: "memory");   // bf1 ready
        __builtin_amdgcn_sched_barrier(0);
        __builtin_amdgcn_s_setprio(1);
        MFMA_Q(0, 1, bf1);
        __builtin_amdgcn_s_setprio(0);
        RD_A(c, 1);                                          // af1: hides under Q01 drain
        __builtin_amdgcn_sched_barrier(0);
        __builtin_amdgcn_s_barrier();                        // BAR1
        // ---------------- phase B ----------------
        if (t + 2 < NT) { STG_B(c, 0, kb2); STG_B(c, 1, kb2); }
        asm volatile("s_waitcnt lgkmcnt(0)" ::: "memory");   // af1 ready
        __builtin_amdgcn_sched_barrier(0);
        __builtin_amdgcn_s_setprio(1);
        MFMA_Q(1, 0, bf0);
        MFMA_Q(1, 1, bf1);
        __builtin_amdgcn_s_setprio(0);
        if (t + 1 < NT) {
            if (t + 2 < NT) { asm volatile("s_waitcnt vmcnt(4)" ::: "memory"); }
            else            { asm volatile("s_waitcnt vmcnt(0)" ::: "memory"); }
            __builtin_amdgcn_sched_barrier(0);
            RD_A(n, 0); RD_B(n, 0, bf0); RD_B(n, 1, bf1);    // next tile's operands
            __builtin_amdgcn_sched_barrier(0);
        }
        __builtin_amdgcn_s_barrier();                        // BAR2
    }
#undef STG_A
#undef STG_B
#undef RD_A
#undef RD_B
#undef MFMA_Q

#pragma unroll
    for (int fr = 0; fr < 8; ++fr) {
        const int row = row0 + wm * 128 + fr * 16 + quad * 4;
#pragma unroll
        for (int fc = 0; fc < 4; ++fc) {
            const int col = col0 + wn * 64 + fc * 16 + l16;
#pragma unroll
            for (int r = 0; r < 4; ++r) {
                const size_t idx = (size_t)(row + r) * N + col;
                float v = acc[fr][fc][r];
                if (EPI == 1) {
                    Cout[idx] = v + res[idx];
                } else if (EPI == 2) {
                    const float gg = res[idx];
                    hout[idx] = (bf16)(gg * (1.f / (1.f + __expf(-gg))) * v);
                } else {
                    Cout[idx] = v;
                }
            }
        }
    }
}

// ---------------------------------------------------------------------------
// prenorm+concat: xcat[row,0:1024]=rmsnorm(emb), [1024:2048]=rmsnorm(hid)
// ---------------------------------------------------------------------------
__global__ __launch_bounds__(256) void prenorm_kernel(
    const float* __restrict__ emb, const float* __restrict__ hid,
    const float* __restrict__ we, const float* __restrict__ wh,
    bf16* __restrict__ xcat)
{
    const int rr = blockIdx.x * 4 + (threadIdx.x >> 6);
    const int lane = threadIdx.x & 63;
    const int half = rr & 1, row = rr >> 1;
    const float* x = (half ? hid : emb) + (size_t)row * 1024;
    const float* w = half ? wh : we;
    float4 v[4]; float ss = 0.f;
#pragma unroll
    for (int j = 0; j < 4; ++j) {
        v[j] = *(const float4*)(x + (size_t)(lane + 64 * j) * 4);
        ss += v[j].x * v[j].x + v[j].y * v[j].y + v[j].z * v[j].z + v[j].w * v[j].w;
    }
#pragma unroll
    for (int m = 32; m; m >>= 1) ss += __shfl_xor(ss, m, 64);
    const float rms = rsqrtf(ss * (1.f / 1024.f) + 1e-6f);
    bf16* o = xcat + (size_t)row * 2048 + half * 1024;
#pragma unroll
    for (int j = 0; j < 4; ++j) {
        const int d = (lane + 64 * j) * 4;
        float4 wv = *(const float4*)(w + d);
        bf16x4 t;
        t[0] = (bf16)(v[j].x * rms * wv.x);
        t[1] = (bf16)(v[j].y * rms * wv.y);
        t[2] = (bf16)(v[j].z * rms * wv.z);
        t[3] = (bf16)(v[j].w * rms * wv.w);
        *(bf16x4*)(o + d) = t;
    }
}

// rmsnorm over H=1024, f32 in -> bf16 out, one wave per row
__global__ __launch_bounds__(256) void rmsnorm_kernel(
    const float* __restrict__ xin, const float* __restrict__ w, bf16* __restrict__ out)
{
    const int row = blockIdx.x * 4 + (threadIdx.x >> 6);
    const int lane = threadIdx.x & 63;
    const float* x = xin + (size_t)row * 1024;
    float4 v[4]; float ss = 0.f;
#pragma unroll
    for (int j = 0; j < 4; ++j) {
        v[j] = *(const float4*)(x + (size_t)(lane + 64 * j) * 4);
        ss += v[j].x * v[j].x + v[j].y * v[j].y + v[j].z * v[j].z + v[j].w * v[j].w;
    }
#pragma unroll
    for (int m = 32; m; m >>= 1) ss += __shfl_xor(ss, m, 64);
    const float rms = rsqrtf(ss * (1.f / 1024.f) + 1e-6f);
    bf16* o = out + (size_t)row * 1024;
#pragma unroll
    for (int j = 0; j < 4; ++j) {
        const int d = (lane + 64 * j) * 4;
        float4 wv = *(const float4*)(w + d);
        bf16x4 t;
        t[0] = (bf16)(v[j].x * rms * wv.x);
        t[1] = (bf16)(v[j].y * rms * wv.y);
        t[2] = (bf16)(v[j].z * rms * wv.z);
        t[3] = (bf16)(v[j].w * rms * wv.w);
        *(bf16x4*)(o + d) = t;
    }
}

// ---------------------------------------------------------------------------
// q prep: rmsnorm(D=256) -> rope(first 64, interleaved) -> *1/16 -> bf16
// ---------------------------------------------------------------------------
__global__ __launch_bounds__(256) void qprep_kernel(
    const float* __restrict__ qg, const float* __restrict__ qn_w, bf16* __restrict__ qa)
{
    const int row = blockIdx.x * 4 + (threadIdx.x >> 6);  // (b*L+l)*8+h
    const int lane = threadIdx.x & 63;
    const int h = row & 7, bl = row >> 3;
    const int l = bl & 2047, b = bl >> 11;
    const float* x = qg + (size_t)row * 512;
    float v[4]; float ss = 0.f;
#pragma unroll
    for (int j = 0; j < 4; ++j) { v[j] = x[lane + 64 * j]; ss += v[j] * v[j]; }
#pragma unroll
    for (int m = 32; m; m >>= 1) ss += __shfl_xor(ss, m, 64);
    const float rms = rsqrtf(ss * (1.f / 256.f) + 1e-6f);
    float y[4];
#pragma unroll
    for (int j = 0; j < 4; ++j) y[j] = v[j] * rms * qn_w[lane + 64 * j];
    {
        const float p = __shfl_xor(y[0], 1, 64);
        const int i2 = lane >> 1;
        const float inv = powf(1e7f, -(float)(2 * i2) * (1.f / 64.f));
        const float ang = (float)l * inv;
        const float c = cosf(ang), s = sinf(ang);
        y[0] = (lane & 1) ? (p * s + y[0] * c) : (y[0] * c - p * s);
    }
    bf16* o = qa + ((size_t)((b * 8 + h) * 2048 + l)) * 256;
#pragma unroll
    for (int j = 0; j < 4; ++j) o[lane + 64 * j] = (bf16)(y[j] * 0.0625f);
}

// k prep: same minus scale; (B,L,NKV,D) f32 -> (B,NKV,L,D) bf16
__global__ __launch_bounds__(256) void kprep_kernel(
    const float* __restrict__ kf, const float* __restrict__ kn_w, bf16* __restrict__ ka)
{
    const int row = blockIdx.x * 4 + (threadIdx.x >> 6);  // (b*L+l)*2+kv
    const int lane = threadIdx.x & 63;
    const int kv = row & 1, bl = row >> 1;
    const int l = bl & 2047, b = bl >> 11;
    const float* x = kf + (size_t)row * 256;
    float v[4]; float ss = 0.f;
#pragma unroll
    for (int j = 0; j < 4; ++j) { v[j] = x[lane + 64 * j]; ss += v[j] * v[j]; }
#pragma unroll
    for (int m = 32; m; m >>= 1) ss += __shfl_xor(ss, m, 64);
    const float rms = rsqrtf(ss * (1.f / 256.f) + 1e-6f);
    float y[4];
#pragma unroll
    for (int j = 0; j < 4; ++j) y[j] = v[j] * rms * kn_w[lane + 64 * j];
    {
        const float p = __shfl_xor(y[0], 1, 64);
        const int i2 = lane >> 1;
        const float inv = powf(1e7f, -(float)(2 * i2) * (1.f / 64.f));
        const float ang = (float)l * inv;
        const float c = cosf(ang), s = sinf(ang);
        y[0] = (lane & 1) ? (p * s + y[0] * c) : (y[0] * c - p * s);
    }
    bf16* o = ka + ((size_t)((b * 2 + kv) * 2048 + l)) * 256;
#pragma unroll
    for (int j = 0; j < 4; ++j) o[lane + 64 * j] = (bf16)y[j];
}

// v prep: (B,L,NKV,D) f32 -> (B,NKV,D,L) bf16 via LDS 64x64 tile transpose.
__global__ __launch_bounds__(256) void vprep_kernel(const float* __restrict__ vf,
                                                    bf16* __restrict__ vt)
{
    __shared__ float t[64][65];
    const int l0 = blockIdx.x << 6;
    const int d0 = blockIdx.y << 6;
    const int b = blockIdx.z >> 1, kv = blockIdx.z & 1;
    const int tx = threadIdx.x & 63, ty = threadIdx.x >> 6;
    const float* src = vf + ((size_t)b * 4096 + kv) * 256;
#pragma unroll
    for (int j = 0; j < 16; ++j) {
        const int l = ty + j * 4;
        t[l][tx] = src[(size_t)(l0 + l) * 512 + d0 + tx];
    }
    __syncthreads();
    bf16* dst = vt + (size_t)(b * 2 + kv) * 256 * 2048;
#pragma unroll
    for (int j = 0; j < 16; ++j) {
        const int d = ty + j * 4;
        dst[(size_t)(d0 + d) * 2048 + l0 + tx] = (bf16)t[tx][d];
    }
}

// ---------------------------------------------------------------------------
// flash attention, balanced pairing + FUSED GATING epilogue.
// 1 block = (b, h, q-tile pair {j, 31-j}) -> uniform 66 kv-tiles/block.
// Epilogue writes ag[(b,l,h*256+d)] = bf16(o * sigmoid(qg_gate)) directly
// (replaces the separate gating kernel; of f32 intermediate eliminated).
// ---------------------------------------------------------------------------
__global__ __launch_bounds__(256) void attn_kernel(
    const bf16* __restrict__ qa, const bf16* __restrict__ ka,
    const bf16* __restrict__ vt, const float* __restrict__ qg,
    bf16* __restrict__ ag)
{
    __shared__ bf16 Ks[32 * 264];
    __shared__ bf16 Vt[256 * 40];
    __shared__ bf16 Pw[4 * 16 * 40];
    const int tid = threadIdx.x;
    const int wave = tid >> 6, lane = tid & 63;
    const int quad = lane >> 4, l16 = lane & 15;
    const int bid = blockIdx.x;
    const int j = bid & 15, h = (bid >> 4) & 7, b = bid >> 7;
    const int kvh = h >> 2;
    const bf16* qptr = qa + ((size_t)(b * 8 + h)) * 2048 * 256;
    const bf16* kptr = ka + ((size_t)(b * 2 + kvh)) * 2048 * 256;
    const bf16* vptr = vt + ((size_t)(b * 2 + kvh)) * 256 * 2048;

    for (int s = 0; s < 2; ++s) {
        const int qt = s ? (31 - j) : j;
        const int qbase = qt * 64 + wave * 16;

        bf16x8 qf[8];
#pragma unroll
        for (int db = 0; db < 8; ++db)
            qf[db] = *(const bf16x8*)(qptr + (size_t)(qbase + l16) * 256 + db * 32 + quad * 8);

        f32x4 o_acc[16] = {};
        float m_i[4], l_i[4];
#pragma unroll
        for (int r = 0; r < 4; ++r) { m_i[r] = -1e30f; l_i[r] = 0.f; }

        const int ntiles = qt * 2 + 2;
        for (int kt = 0; kt < ntiles; ++kt) {
            const int kvs = kt * 32;
#pragma unroll
            for (int c = 0; c < 4; ++c) {
                const int idx = tid + c * 256;
                const int kr = idx >> 5, kc = (idx & 31) * 8;
                *(bf16x8*)(&Ks[kr * 264 + kc]) = *(const bf16x8*)(kptr + (size_t)(kvs + kr) * 256 + kc);
                const int vd = idx >> 2, vc = (idx & 3) * 8;
                *(bf16x8*)(&Vt[vd * 40 + vc]) = *(const bf16x8*)(vptr + (size_t)vd * 2048 + kvs + vc);
            }
            __syncthreads();

            f32x4 s0 = {}, s1 = {};
#pragma unroll
            for (int db = 0; db < 8; ++db) {
                bf16x8 k0 = *(const bf16x8*)(&Ks[l16 * 264 + db * 32 + quad * 8]);
                bf16x8 k1 = *(const bf16x8*)(&Ks[(16 + l16) * 264 + db * 32 + quad * 8]);
                s0 = mfma16(qf[db], k0, s0);
                s1 = mfma16(qf[db], k1, s1);
            }

            float alpha[4], p0v[4], p1v[4];
#pragma unroll
            for (int r = 0; r < 4; ++r) {
                const int qrow = qbase + quad * 4 + r;
                float a0 = (kvs + l16 > qrow) ? -1e30f : s0[r];
                float a1 = (kvs + 16 + l16 > qrow) ? -1e30f : s1[r];
                float mx = fmaxf(a0, a1);
#pragma unroll
                for (int m = 8; m; m >>= 1) mx = fmaxf(mx, __shfl_xor(mx, m, 64));
                const float mnew = fmaxf(m_i[r], mx);
                const float a = __expf(m_i[r] - mnew);
                const float p0 = __expf(a0 - mnew);
                const float p1 = __expf(a1 - mnew);
                float ps = p0 + p1;
#pragma unroll
                for (int m = 8; m; m >>= 1) ps += __shfl_xor(ps, m, 64);
                l_i[r] = l_i[r] * a + ps;
                m_i[r] = mnew;
                alpha[r] = a; p0v[r] = p0; p1v[r] = p1;
            }
#pragma unroll
            for (int t = 0; t < 16; ++t) {
                f32x4 o = o_acc[t];
                o[0] *= alpha[0]; o[1] *= alpha[1]; o[2] *= alpha[2]; o[3] *= alpha[3];
                o_acc[t] = o;
            }
            bf16* pw = &Pw[wave * 16 * 40];
#pragma unroll
            for (int r = 0; r < 4; ++r) {
                pw[(quad * 4 + r) * 40 + l16]      = (bf16)p0v[r];
                pw[(quad * 4 + r) * 40 + 16 + l16] = (bf16)p1v[r];
            }
            __syncthreads();
            const bf16x8 pa = *(const bf16x8*)(&pw[l16 * 40 + quad * 8]);
#pragma unroll
            for (int t = 0; t < 16; ++t) {
                bf16x8 vfr = *(const bf16x8*)(&Vt[(t * 16 + l16) * 40 + quad * 8]);
                o_acc[t] = mfma16(pa, vfr, o_acc[t]);
            }
            __syncthreads();
        }

        // fused gating epilogue: ag[(b,row,h*256+d)] = bf16(o * sigmoid(gate))
#pragma unroll
        for (int r = 0; r < 4; ++r) {
            const float inv = 1.f / l_i[r];
            const int row = qbase + quad * 4 + r;
            const float* gr = qg + ((size_t)((b * 2048 + row) * 8 + h)) * 512 + 256;
            bf16* ar = ag + ((size_t)(b * 2048 + row)) * 2048 + h * 256;
#pragma unroll
            for (int t = 0; t < 16; ++t) {
                const int d = t * 16 + l16;
                const float o = o_acc[t][r] * inv;
                const float gg = gr[d];
                ar[d] = (bf16)(o * (1.f / (1.f + __expf(-gg))));
            }
        }
    }
}

// ---------------------------------------------------------------------------
extern "C" void kernel_launch(void* const* d_in, const int* in_sizes, int n_in,
                              void* d_out, int out_size, void* d_ws, size_t ws_size,
                              hipStream_t stream)
{
    const float* emb       = (const float*)d_in[0];
    const float* hid       = (const float*)d_in[1];
    const float* pre_emb_w = (const float*)d_in[2];
    const float* pre_hid_w = (const float*)d_in[3];
    const float* fc_w      = (const float*)d_in[4];
    const float* in_ln_w   = (const float*)d_in[5];
    const float* q_w       = (const float*)d_in[6];
    const float* k_w       = (const float*)d_in[7];
    const float* v_w       = (const float*)d_in[8];
    const float* o_w       = (const float*)d_in[9];
    const float* qn_w      = (const float*)d_in[10];
    const float* kn_w      = (const float*)d_in[11];
    const float* post_ln_w = (const float*)d_in[12];
    const float* gate_w    = (const float*)d_in[13];
    const float* up_w      = (const float*)d_in[14];
    const float* down_w    = (const float*)d_in[15];
    const float* norm_w    = (const float*)d_in[16];
    const float* lm_w      = (const float*)d_in[17];
    float* out = (float*)d_out;
    char* ws = (char*)d_ws;

    // workspace layout (lifetime-overlapped), total 360 MiB (unchanged)
    float* xres = (float*)(ws + 0);                 // 32 MiB, residual (in-place)
    bf16*  xln  = (bf16*)(ws + 33554432);           // 16 MiB, reused 3x
    char*  C    = ws + 50331648;                    // 128 MiB: qg then gate_f32 (+ wb slots)
    char*  D    = ws + 184549376;                   // 128 MiB: xcat/kf/vf then ag
    char*  E    = ws + 318767104;                   // 56 MiB: qa/ka/va then h
    float* qg   = (float*)C;
    float* gf   = (float*)C;
    bf16*  xcat = (bf16*)D;
    float* kf   = (float*)(D + 33554432);
    float* vf   = (float*)(D + 50331648);
    bf16*  ag   = (bf16*)(D + 67108864);     // 32 MiB (old `of` slot; NOT aliasing qa)
    bf16*  qa   = (bf16*)E;
    bf16*  ka   = (bf16*)(E + 33554432);
    bf16*  va   = (bf16*)(E + 41943040);
    bf16*  hb   = (bf16*)E;                  // 56 MiB, written after qa/ka/va are dead
    // bf16 weight scratch slots (placed in regions dead at time of use)
    bf16*  wbC  = (bf16*)C;                  // fc(4M), o(4M), down(7M), lm(32M)
    bf16*  wbD  = (bf16*)D;                  // q(8M), k(1M), v(1M)
    bf16*  wbDt = (bf16*)(D + 117440512);    // gate(7M), up(7M) — above ag

    prenorm_kernel<<<4096, 256, 0, stream>>>(emb, hid, pre_emb_w, pre_hid_w, xcat);

    w2b_kernel<<<2048, 256, 0, stream>>>(fc_w, wbC);                       // 1024x2048
    gemm_kernel<0><<<512, 256, 0, stream>>>(xcat, wbC, nullptr, xres, 8192, 1024, 2048);
    rmsnorm_kernel<<<2048, 256, 0, stream>>>(xres, in_ln_w, xln);

    w2b_kernel<<<4096, 256, 0, stream>>>(q_w, wbD);                        // 4096x1024
    gemm256_kernel<0><<<512, 512, 0, stream>>>(xln, wbD, nullptr, qg, nullptr, 8192, 4096, 1024);
    w2b_kernel<<<512, 256, 0, stream>>>(k_w, wbD);                         // 512x1024
    gemm_kernel<0><<<256, 256, 0, stream>>>(xln, wbD, nullptr, kf, 8192, 512, 1024);
    w2b_kernel<<<512, 256, 0, stream>>>(v_w, wbD);
    gemm_kernel<0><<<256, 256, 0, stream>>>(xln, wbD, nullptr, vf, 8192, 512, 1024);

    qprep_kernel<<<16384, 256, 0, stream>>>(qg, qn_w, qa);
    kprep_kernel<<<4096, 256, 0, stream>>>(kf, kn_w, ka);
    vprep_kernel<<<dim3(32, 4, 8), 256, 0, stream>>>(vf, va);
    attn_kernel<<<512, 256, 0, stream>>>(qa, ka, va, qg, ag);   // fused gating

    w2b_kernel<<<2048, 256, 0, stream>>>(o_w, wbC);                        // 1024x2048
    gemm_kernel<1><<<512, 256, 0, stream>>>(ag, wbC, xres, xres, 8192, 1024, 2048);
    rmsnorm_kernel<<<2048, 256, 0, stream>>>(xres, post_ln_w, xln);

    w2b_kernel<<<3584, 256, 0, stream>>>(gate_w, wbDt);                    // 3584x1024
    gemm256_kernel<0><<<448, 512, 0, stream>>>(xln, wbDt, nullptr, gf, nullptr, 8192, 3584, 1024);
    w2b_kernel<<<3584, 256, 0, stream>>>(up_w, wbDt);
    gemm256_kernel<2><<<448, 512, 0, stream>>>(xln, wbDt, gf, nullptr, hb, 8192, 3584, 1024);  // fused silu*up

    w2b_kernel<<<3584, 256, 0, stream>>>(down_w, wbC);                     // 1024x3584
    gemm_kernel<1><<<512, 256, 0, stream>>>(hb, wbC, xres, xres, 8192, 1024, 3584);
    rmsnorm_kernel<<<2048, 256, 0, stream>>>(xres, norm_w, xln);

    w2b_kernel<<<16384, 256, 0, stream>>>(lm_w, wbC);                      // 16384x1024
    gemm256_kernel<0><<<2048, 512, 0, stream>>>(xln, wbC, nullptr, out, nullptr, 8192, 16384, 1024);
}

// Round 7
// 1728.099 us; speedup vs baseline: 1.1114x; 1.0340x over previous
//
#include <hip/hip_runtime.h>

typedef __bf16 bf16;
typedef __bf16 bf16x8 __attribute__((ext_vector_type(8)));
typedef __bf16 bf16x4 __attribute__((ext_vector_type(4)));
typedef float f32x4 __attribute__((ext_vector_type(4)));

__device__ inline f32x4 mfma16(bf16x8 a, bf16x8 b, f32x4 c) {
    return __builtin_amdgcn_mfma_f32_16x16x32_bf16(a, b, c, 0, 0, 0);
}

// async global->LDS, 16B per lane. LDS dest is wave-uniform base + lane*16.
__device__ __forceinline__ void async_cp16(const void* g, void* l) {
    __builtin_amdgcn_global_load_lds(
        (__attribute__((address_space(1))) char*)g,
        (__attribute__((address_space(3))) char*)l,
        16, 0, 0);
}

// f32 -> bf16 weight conversion, vec4. grid = n/1024 blocks.
__global__ __launch_bounds__(256) void w2b_kernel(const float* __restrict__ s,
                                                  bf16* __restrict__ d)
{
    const size_t i = ((size_t)blockIdx.x * 256 + threadIdx.x) * 4;
    const float4 f = *(const float4*)(s + i);
    bf16x4 t;
    t[0] = (bf16)f.x; t[1] = (bf16)f.y; t[2] = (bf16)f.z; t[3] = (bf16)f.w;
    *(bf16x4*)(d + i) = t;
}

// merged q/k/v weight conversion: q(4096 blk) -> dq, k(512) -> dq+4M, v(512) -> +4.5M
__global__ __launch_bounds__(256) void w2b_qkv_kernel(
    const float* __restrict__ qw, const float* __restrict__ kw,
    const float* __restrict__ vw, bf16* __restrict__ dq)
{
    int bid = blockIdx.x;
    const float* s; bf16* d;
    if (bid < 4096)      { s = qw; d = dq; }
    else if (bid < 4608) { s = kw; d = dq + 4194304; bid -= 4096; }
    else                 { s = vw; d = dq + 4718592; bid -= 4608; }
    const size_t i = ((size_t)bid * 256 + threadIdx.x) * 4;
    const float4 f = *(const float4*)(s + i);
    bf16x4 t;
    t[0] = (bf16)f.x; t[1] = (bf16)f.y; t[2] = (bf16)f.z; t[3] = (bf16)f.w;
    *(bf16x4*)(d + i) = t;
}

// merged gate/up weight conversion: gate(3584 blk) -> dg, up(3584) -> dg+3.5M
__global__ __launch_bounds__(256) void w2b_gu_kernel(
    const float* __restrict__ gw, const float* __restrict__ uw, bf16* __restrict__ dg)
{
    int bid = blockIdx.x;
    const float* s; bf16* d;
    if (bid < 3584) { s = gw; d = dg; }
    else            { s = uw; d = dg + 3670016; bid -= 3584; }
    const size_t i = ((size_t)bid * 256 + threadIdx.x) * 4;
    const float4 f = *(const float4*)(s + i);
    bf16x4 t;
    t[0] = (bf16)f.x; t[1] = (bf16)f.y; t[2] = (bf16)f.z; t[3] = (bf16)f.w;
    *(bf16x4*)(d + i) = t;
}

// ---------------------------------------------------------------------------
// 128x128-tile GEMM v2: BK=64 (half the barriers of BK=32) + T2 XOR swizzle
// (same 8-chunk scheme as gemm256; kills the 8-way bank conflict measured at
// 3.36e7 in the BK=32 version). 2-barrier structure, single LDS buffer 32KiB.
// These GEMMs are grid-limited (2 blocks/CU), so extra LDS costs nothing.
// C(MxN) = A(MxK)bf16 @ B(NxK)bf16^T, f32 accum. EPI1 adds residual.
// ---------------------------------------------------------------------------
template <int EPI>
__global__ __launch_bounds__(256) void gemm_kernel(
    const bf16* __restrict__ A, const bf16* __restrict__ B,
    const float* __restrict__ res, float* __restrict__ Cout,
    int M, int N, int K)
{
    __shared__ bf16 As[128][64];
    __shared__ bf16 Bs[128][64];
    const int tid = threadIdx.x;
    const int wave = tid >> 6, lane = tid & 63;
    const int quad = lane >> 4, l16 = lane & 15;
    const int xsw = l16 & 7;

    const int nby = M >> 7, nbx = N >> 7;
    const int nwg = nbx * nby;
    int bid = blockIdx.x;
    {
        const int q = nwg >> 3, r = nwg & 7;
        const int x = bid & 7, loc = bid >> 3;
        bid = (x < r ? x * (q + 1) : r * (q + 1) + (x - r) * q) + loc;
    }
    const int pg = nbx << 3;
    const int g = bid / pg, rem = bid - g * pg;
    const int by = (g << 3) + (rem & 7);
    const int bx = rem >> 3;
    const int row0 = by << 7, col0 = bx << 7;
    const int wrow = ((wave >> 1) << 6), wcol = ((wave & 1) << 6);

    f32x4 acc[4][4] = {};

    // staging: thread t -> row t>>3 (+32 per call), chunk (t&7)^(row&7)
    const int srow = tid >> 3;
    const int scol = ((tid & 7) ^ (srow & 7)) * 8;
    const bf16* Ag = A + (size_t)(row0 + srow) * K + scol;
    const bf16* Bg = B + (size_t)(col0 + srow) * K + scol;
    const size_t K32 = (size_t)32 * K;

    for (int kb = 0; kb < K; kb += 64) {
#pragma unroll
        for (int q = 0; q < 4; ++q) {
            async_cp16(Ag + q * K32 + kb, &As[0][0] + q * 2048 + wave * 512);
            async_cp16(Bg + q * K32 + kb, &Bs[0][0] + q * 2048 + wave * 512);
        }
        __syncthreads();
        bf16x8 af[8], bfr[8];
#pragma unroll
        for (int i = 0; i < 4; ++i) {
            af[i * 2 + 0] = *(const bf16x8*)(&As[wrow + i * 16 + l16][(quad ^ xsw) * 8]);
            af[i * 2 + 1] = *(const bf16x8*)(&As[wrow + i * 16 + l16][((4 + quad) ^ xsw) * 8]);
        }
#pragma unroll
        for (int j = 0; j < 4; ++j) {
            bfr[j * 2 + 0] = *(const bf16x8*)(&Bs[wcol + j * 16 + l16][(quad ^ xsw) * 8]);
            bfr[j * 2 + 1] = *(const bf16x8*)(&Bs[wcol + j * 16 + l16][((4 + quad) ^ xsw) * 8]);
        }
#pragma unroll
        for (int i = 0; i < 4; ++i)
#pragma unroll
            for (int j = 0; j < 4; ++j) {
                acc[i][j] = mfma16(af[i * 2 + 0], bfr[j * 2 + 0], acc[i][j]);
                acc[i][j] = mfma16(af[i * 2 + 1], bfr[j * 2 + 1], acc[i][j]);
            }
        __syncthreads();
    }

#pragma unroll
    for (int i = 0; i < 4; ++i) {
        const int row = row0 + wrow + i * 16 + quad * 4;
#pragma unroll
        for (int j = 0; j < 4; ++j) {
            const int col = col0 + wcol + j * 16 + l16;
#pragma unroll
            for (int r = 0; r < 4; ++r) {
                const size_t idx = (size_t)(row + r) * N + col;
                float v = acc[i][j][r];
                if (EPI == 1) Cout[idx] = v + res[idx];
                else          Cout[idx] = v;
            }
        }
    }
}

// ---------------------------------------------------------------------------
// 256x256-tile GEMM, v3: 2-barrier counted-pipeline per K-tile (see R4 notes).
// EPI: 0 = f32 out; 1 = f32 out + residual; 2 = hout = bf16(silu(res)*acc)
// ---------------------------------------------------------------------------
template <int EPI>
__global__ __launch_bounds__(512, 2) void gemm256_kernel(
    const bf16* __restrict__ A, const bf16* __restrict__ B,
    const float* __restrict__ res, float* __restrict__ Cout,
    bf16* __restrict__ hout, int M, int N, int K)
{
    __shared__ bf16 As[2][2][128][64];
    __shared__ bf16 Bs[2][2][128][64];
    const int tid = threadIdx.x;
    const int wid = tid >> 6, lane = tid & 63;
    const int quad = lane >> 4, l16 = lane & 15;
    const int wm = wid >> 2, wn = wid & 3;
    const int xsw = l16 & 7;
    const int bofs = (wn & 1) * 64;

    const int nby = M >> 8, nbx = N >> 8;
    const int nwg = nbx * nby;
    int bid = blockIdx.x;
    {
        const int q = nwg >> 3, r = nwg & 7;
        const int x = bid & 7, loc = bid >> 3;
        bid = (x < r ? x * (q + 1) : r * (q + 1) + (x - r) * q) + loc;
    }
    const int pg = nbx << 3;
    const int g = bid / pg, rem = bid - g * pg;
    const int by = (g << 3) + (rem & 7);
    const int bx = rem >> 3;
    const int row0 = by << 8, col0 = bx << 8;

    const int srow = tid >> 3;
    const int scol = ((tid & 7) ^ ((tid >> 3) & 7)) * 8;
    const bf16* Abase = A + (size_t)(row0 + srow) * K + scol;
    const bf16* Bbase = B + (size_t)(col0 + srow) * K + scol;
    const size_t K64 = (size_t)K * 64;
    const size_t K128 = (size_t)K * 128;

    f32x4 acc[8][4] = {};
    bf16x8 af[8], bf0[4], bf1[4];

#define STG_A(BUF, HH, KB) do { \
    const bf16* _g = Abase + (size_t)(HH) * K128 + (KB); \
    bf16* _l = &As[BUF][HH][0][0] + wid * 512; \
    async_cp16(_g, _l); \
    async_cp16(_g + K64, _l + 4096); } while (0)
#define STG_B(BUF, HH, KB) do { \
    const bf16* _g = Bbase + (size_t)(HH) * K128 + (KB); \
    bf16* _l = &Bs[BUF][HH][0][0] + wid * 512; \
    async_cp16(_g, _l); \
    async_cp16(_g + K64, _l + 4096); } while (0)

#define RD_A(BUF, RH) do { \
    const bf16 (*Ah_)[64] = As[BUF][wm]; \
    _Pragma("unroll") for (int f = 0; f < 4; ++f) { \
        af[f*2+0] = *(const bf16x8*)(&Ah_[(RH)*64 + f*16 + l16][(quad ^ xsw) * 8]); \
        af[f*2+1] = *(const bf16x8*)(&Ah_[(RH)*64 + f*16 + l16][((4 + quad) ^ xsw) * 8]); } } while (0)

#define RD_B(BUF, CH, BF) do { \
    const bf16 (*Bh_)[64] = Bs[BUF][wn >> 1]; \
    _Pragma("unroll") for (int f = 0; f < 2; ++f) { \
        BF[f*2+0] = *(const bf16x8*)(&Bh_[bofs + (CH)*32 + f*16 + l16][(quad ^ xsw) * 8]); \
        BF[f*2+1] = *(const bf16x8*)(&Bh_[bofs + (CH)*32 + f*16 + l16][((4 + quad) ^ xsw) * 8]); } } while (0)

#define MFMA_Q(RH, CH, BF) do { \
    _Pragma("unroll") for (int f = 0; f < 4; ++f) \
    _Pragma("unroll") for (int f2 = 0; f2 < 2; ++f2) { \
        acc[(RH)*4+f][(CH)*2+f2] = mfma16(af[f*2+0], BF[f2*2+0], acc[(RH)*4+f][(CH)*2+f2]); \
        acc[(RH)*4+f][(CH)*2+f2] = mfma16(af[f*2+1], BF[f2*2+1], acc[(RH)*4+f][(CH)*2+f2]); } } while (0)

    const int NT = K >> 6;
    STG_A(0, 0, 0); STG_A(0, 1, 0); STG_B(0, 0, 0); STG_B(0, 1, 0);
    if (NT > 1) {
        STG_A(1, 0, 64); STG_A(1, 1, 64); STG_B(1, 0, 64); STG_B(1, 1, 64);
        asm volatile("s_waitcnt vmcnt(8)" ::: "memory");
    } else {
        asm volatile("s_waitcnt vmcnt(0)" ::: "memory");
    }
    __builtin_amdgcn_sched_barrier(0);
    __builtin_amdgcn_s_barrier();
    RD_A(0, 0); RD_B(0, 0, bf0); RD_B(0, 1, bf1);
    __builtin_amdgcn_sched_barrier(0);

    for (int t = 0; t < NT; ++t) {
        const int c = t & 1, n = c ^ 1;
        const int kb1 = (t + 1) << 6, kb2 = (t + 2) << 6;
        // ---------------- phase A ----------------
        if (t >= 1 && t + 1 < NT) { STG_A(n, 0, kb1); STG_A(n, 1, kb1); }
        asm volatile("s_waitcnt lgkmcnt(4)" ::: "memory");   // af0+bf0 ready
        __builtin_amdgcn_sched_barrier(0);
        __builtin_amdgcn_s_setprio(1);
        MFMA_Q(0, 0, bf0);
        __builtin_amdgcn_s_setprio(0);
        asm volatile("s_waitcnt lgkmcnt(0)" ::: "memory");   // bf1 ready
        __builtin_amdgcn_sched_barrier(0);
        __builtin_amdgcn_s_setprio(1);
        MFMA_Q(0, 1, bf1);
        __builtin_amdgcn_s_setprio(0);
        RD_A(c, 1);                                          // af1: hides under Q01 drain
        __builtin_amdgcn_sched_barrier(0);
        __builtin_amdgcn_s_barrier();                        // BAR1
        // ---------------- phase B ----------------
        if (t + 2 < NT) { STG_B(c, 0, kb2); STG_B(c, 1, kb2); }
        asm volatile("s_waitcnt lgkmcnt(0)" ::: "memory");   // af1 ready
        __builtin_amdgcn_sched_barrier(0);
        __builtin_amdgcn_s_setprio(1);
        MFMA_Q(1, 0, bf0);
        MFMA_Q(1, 1, bf1);
        __builtin_amdgcn_s_setprio(0);
        if (t + 1 < NT) {
            if (t + 2 < NT) { asm volatile("s_waitcnt vmcnt(4)" ::: "memory"); }
            else            { asm volatile("s_waitcnt vmcnt(0)" ::: "memory"); }
            __builtin_amdgcn_sched_barrier(0);
            RD_A(n, 0); RD_B(n, 0, bf0); RD_B(n, 1, bf1);    // next tile's operands
            __builtin_amdgcn_sched_barrier(0);
        }
        __builtin_amdgcn_s_barrier();                        // BAR2
    }
#undef STG_A
#undef STG_B
#undef RD_A
#undef RD_B
#undef MFMA_Q

#pragma unroll
    for (int fr = 0; fr < 8; ++fr) {
        const int row = row0 + wm * 128 + fr * 16 + quad * 4;
#pragma unroll
        for (int fc = 0; fc < 4; ++fc) {
            const int col = col0 + wn * 64 + fc * 16 + l16;
#pragma unroll
            for (int r = 0; r < 4; ++r) {
                const size_t idx = (size_t)(row + r) * N + col;
                float v = acc[fr][fc][r];
                if (EPI == 1) {
                    Cout[idx] = v + res[idx];
                } else if (EPI == 2) {
                    const float gg = res[idx];
                    hout[idx] = (bf16)(gg * (1.f / (1.f + __expf(-gg))) * v);
                } else {
                    Cout[idx] = v;
                }
            }
        }
    }
}

// ---------------------------------------------------------------------------
// prenorm+concat: xcat[row,0:1024]=rmsnorm(emb), [1024:2048]=rmsnorm(hid)
// ---------------------------------------------------------------------------
__global__ __launch_bounds__(256) void prenorm_kernel(
    const float* __restrict__ emb, const float* __restrict__ hid,
    const float* __restrict__ we, const float* __restrict__ wh,
    bf16* __restrict__ xcat)
{
    const int rr = blockIdx.x * 4 + (threadIdx.x >> 6);
    const int lane = threadIdx.x & 63;
    const int half = rr & 1, row = rr >> 1;
    const float* x = (half ? hid : emb) + (size_t)row * 1024;
    const float* w = half ? wh : we;
    float4 v[4]; float ss = 0.f;
#pragma unroll
    for (int j = 0; j < 4; ++j) {
        v[j] = *(const float4*)(x + (size_t)(lane + 64 * j) * 4);
        ss += v[j].x * v[j].x + v[j].y * v[j].y + v[j].z * v[j].z + v[j].w * v[j].w;
    }
#pragma unroll
    for (int m = 32; m; m >>= 1) ss += __shfl_xor(ss, m, 64);
    const float rms = rsqrtf(ss * (1.f / 1024.f) + 1e-6f);
    bf16* o = xcat + (size_t)row * 2048 + half * 1024;
#pragma unroll
    for (int j = 0; j < 4; ++j) {
        const int d = (lane + 64 * j) * 4;
        float4 wv = *(const float4*)(w + d);
        bf16x4 t;
        t[0] = (bf16)(v[j].x * rms * wv.x);
        t[1] = (bf16)(v[j].y * rms * wv.y);
        t[2] = (bf16)(v[j].z * rms * wv.z);
        t[3] = (bf16)(v[j].w * rms * wv.w);
        *(bf16x4*)(o + d) = t;
    }
}

// rmsnorm over H=1024, f32 in -> bf16 out, one wave per row
__global__ __launch_bounds__(256) void rmsnorm_kernel(
    const float* __restrict__ xin, const float* __restrict__ w, bf16* __restrict__ out)
{
    const int row = blockIdx.x * 4 + (threadIdx.x >> 6);
    const int lane = threadIdx.x & 63;
    const float* x = xin + (size_t)row * 1024;
    float4 v[4]; float ss = 0.f;
#pragma unroll
    for (int j = 0; j < 4; ++j) {
        v[j] = *(const float4*)(x + (size_t)(lane + 64 * j) * 4);
        ss += v[j].x * v[j].x + v[j].y * v[j].y + v[j].z * v[j].z + v[j].w * v[j].w;
    }
#pragma unroll
    for (int m = 32; m; m >>= 1) ss += __shfl_xor(ss, m, 64);
    const float rms = rsqrtf(ss * (1.f / 1024.f) + 1e-6f);
    bf16* o = out + (size_t)row * 1024;
#pragma unroll
    for (int j = 0; j < 4; ++j) {
        const int d = (lane + 64 * j) * 4;
        float4 wv = *(const float4*)(w + d);
        bf16x4 t;
        t[0] = (bf16)(v[j].x * rms * wv.x);
        t[1] = (bf16)(v[j].y * rms * wv.y);
        t[2] = (bf16)(v[j].z * rms * wv.z);
        t[3] = (bf16)(v[j].w * rms * wv.w);
        *(bf16x4*)(o + d) = t;
    }
}

// ---------------------------------------------------------------------------
// q prep, vectorized: one float4 per lane (d = 4*lane..4*lane+3).
// rmsnorm(D=256) -> rope (pairs lie INSIDE the float4; lanes 0-15 only)
// -> *1/16 -> bf16x4 store. layout (B,L,NQ,2,D) f32 -> (B,NQ,L,D) bf16.
// ---------------------------------------------------------------------------
__global__ __launch_bounds__(256) void qprep_kernel(
    const float* __restrict__ qg, const float* __restrict__ qn_w, bf16* __restrict__ qa)
{
    const int row = blockIdx.x * 4 + (threadIdx.x >> 6);  // (b*L+l)*8+h
    const int lane = threadIdx.x & 63;
    const int h = row & 7, bl = row >> 3;
    const int l = bl & 2047, b = bl >> 11;
    const float* x = qg + (size_t)row * 512;
    float4 v = *(const float4*)(x + lane * 4);
    float ss = v.x * v.x + v.y * v.y + v.z * v.z + v.w * v.w;
#pragma unroll
    for (int m = 32; m; m >>= 1) ss += __shfl_xor(ss, m, 64);
    const float rms = rsqrtf(ss * (1.f / 256.f) + 1e-6f);
    const float4 wv = *(const float4*)(qn_w + lane * 4);
    float y0 = v.x * rms * wv.x, y1 = v.y * rms * wv.y;
    float y2 = v.z * rms * wv.z, y3 = v.w * rms * wv.w;
    if (lane < 16) {  // d = 4*lane+e < 64: rope pairs (y0,y1) i2=2*lane, (y2,y3) i2=2*lane+1
        const float inv0 = powf(1e7f, -(float)(4 * lane) * (1.f / 64.f));
        const float inv1 = powf(1e7f, -(float)(4 * lane + 2) * (1.f / 64.f));
        const float a0 = (float)l * inv0, a1 = (float)l * inv1;
        const float c0 = cosf(a0), s0 = sinf(a0), c1 = cosf(a1), s1 = sinf(a1);
        const float r0 = y0 * c0 - y1 * s0, r1 = y0 * s0 + y1 * c0;
        const float r2 = y2 * c1 - y3 * s1, r3 = y2 * s1 + y3 * c1;
        y0 = r0; y1 = r1; y2 = r2; y3 = r3;
    }
    bf16* o = qa + ((size_t)((b * 8 + h) * 2048 + l)) * 256 + lane * 4;
    bf16x4 t;
    t[0] = (bf16)(y0 * 0.0625f); t[1] = (bf16)(y1 * 0.0625f);
    t[2] = (bf16)(y2 * 0.0625f); t[3] = (bf16)(y3 * 0.0625f);
    *(bf16x4*)o = t;
}

// k prep, vectorized: same minus scale. input kvf rows are 1024 wide
// (merged k|v GEMM output); k features at cols kv*256..+255.
__global__ __launch_bounds__(256) void kprep_kernel(
    const float* __restrict__ kvf, const float* __restrict__ kn_w, bf16* __restrict__ ka)
{
    const int row = blockIdx.x * 4 + (threadIdx.x >> 6);  // (b*L+l)*2+kv
    const int lane = threadIdx.x & 63;
    const int kv = row & 1, bl = row >> 1;
    const int l = bl & 2047, b = bl >> 11;
    const float* x = kvf + (size_t)bl * 1024 + kv * 256;
    float4 v = *(const float4*)(x + lane * 4);
    float ss = v.x * v.x + v.y * v.y + v.z * v.z + v.w * v.w;
#pragma unroll
    for (int m = 32; m; m >>= 1) ss += __shfl_xor(ss, m, 64);
    const float rms = rsqrtf(ss * (1.f / 256.f) + 1e-6f);
    const float4 wv = *(const float4*)(kn_w + lane * 4);
    float y0 = v.x * rms * wv.x, y1 = v.y * rms * wv.y;
    float y2 = v.z * rms * wv.z, y3 = v.w * rms * wv.w;
    if (lane < 16) {
        const float inv0 = powf(1e7f, -(float)(4 * lane) * (1.f / 64.f));
        const float inv1 = powf(1e7f, -(float)(4 * lane + 2) * (1.f / 64.f));
        const float a0 = (float)l * inv0, a1 = (float)l * inv1;
        const float c0 = cosf(a0), s0 = sinf(a0), c1 = cosf(a1), s1 = sinf(a1);
        const float r0 = y0 * c0 - y1 * s0, r1 = y0 * s0 + y1 * c0;
        const float r2 = y2 * c1 - y3 * s1, r3 = y2 * s1 + y3 * c1;
        y0 = r0; y1 = r1; y2 = r2; y3 = r3;
    }
    bf16* o = ka + ((size_t)((b * 2 + kv) * 2048 + l)) * 256 + lane * 4;
    bf16x4 t;
    t[0] = (bf16)y0; t[1] = (bf16)y1; t[2] = (bf16)y2; t[3] = (bf16)y3;
    *(bf16x4*)o = t;
}

// v prep: merged-layout (rows 1024 wide, v at col 512+kv*256+d)
// -> (B,NKV,D,L) bf16 via LDS 64x64 tile transpose.
__global__ __launch_bounds__(256) void vprep_kernel(const float* __restrict__ kvf,
                                                    bf16* __restrict__ vt)
{
    __shared__ float t[64][65];
    const int l0 = blockIdx.x << 6;
    const int d0 = blockIdx.y << 6;
    const int b = blockIdx.z >> 1, kv = blockIdx.z & 1;
    const int tx = threadIdx.x & 63, ty = threadIdx.x >> 6;
    const float* src = kvf + (size_t)b * 2048 * 1024 + 512 + kv * 256;
#pragma unroll
    for (int j = 0; j < 16; ++j) {
        const int l = ty + j * 4;
        t[l][tx] = src[(size_t)(l0 + l) * 1024 + d0 + tx];
    }
    __syncthreads();
    bf16* dst = vt + (size_t)(b * 2 + kv) * 256 * 2048;
#pragma unroll
    for (int j = 0; j < 16; ++j) {
        const int d = ty + j * 4;
        dst[(size_t)(d0 + d) * 2048 + l0 + tx] = (bf16)t[tx][d];
    }
}

// ---------------------------------------------------------------------------
// flash attention, balanced pairing + FUSED GATING epilogue (unchanged R5).
// ---------------------------------------------------------------------------
__global__ __launch_bounds__(256) void attn_kernel(
    const bf16* __restrict__ qa, const bf16* __restrict__ ka,
    const bf16* __restrict__ vt, const float* __restrict__ qg,
    bf16* __restrict__ ag)
{
    __shared__ bf16 Ks[32 * 264];
    __shared__ bf16 Vt[256 * 40];
    __shared__ bf16 Pw[4 * 16 * 40];
    const int tid = threadIdx.x;
    const int wave = tid >> 6, lane = tid & 63;
    const int quad = lane >> 4, l16 = lane & 15;
    const int bid = blockIdx.x;
    const int j = bid & 15, h = (bid >> 4) & 7, b = bid >> 7;
    const int kvh = h >> 2;
    const bf16* qptr = qa + ((size_t)(b * 8 + h)) * 2048 * 256;
    const bf16* kptr = ka + ((size_t)(b * 2 + kvh)) * 2048 * 256;
    const bf16* vptr = vt + ((size_t)(b * 2 + kvh)) * 256 * 2048;

    for (int s = 0; s < 2; ++s) {
        const int qt = s ? (31 - j) : j;
        const int qbase = qt * 64 + wave * 16;

        bf16x8 qf[8];
#pragma unroll
        for (int db = 0; db < 8; ++db)
            qf[db] = *(const bf16x8*)(qptr + (size_t)(qbase + l16) * 256 + db * 32 + quad * 8);

        f32x4 o_acc[16] = {};
        float m_i[4], l_i[4];
#pragma unroll
        for (int r = 0; r < 4; ++r) { m_i[r] = -1e30f; l_i[r] = 0.f; }

        const int ntiles = qt * 2 + 2;
        for (int kt = 0; kt < ntiles; ++kt) {
            const int kvs = kt * 32;
#pragma unroll
            for (int c = 0; c < 4; ++c) {
                const int idx = tid + c * 256;
                const int kr = idx >> 5, kc = (idx & 31) * 8;
                *(bf16x8*)(&Ks[kr * 264 + kc]) = *(const bf16x8*)(kptr + (size_t)(kvs + kr) * 256 + kc);
                const int vd = idx >> 2, vc = (idx & 3) * 8;
                *(bf16x8*)(&Vt[vd * 40 + vc]) = *(const bf16x8*)(vptr + (size_t)vd * 2048 + kvs + vc);
            }
            __syncthreads();

            f32x4 s0 = {}, s1 = {};
#pragma unroll
            for (int db = 0; db < 8; ++db) {
                bf16x8 k0 = *(const bf16x8*)(&Ks[l16 * 264 + db * 32 + quad * 8]);
                bf16x8 k1 = *(const bf16x8*)(&Ks[(16 + l16) * 264 + db * 32 + quad * 8]);
                s0 = mfma16(qf[db], k0, s0);
                s1 = mfma16(qf[db], k1, s1);
            }

            float alpha[4], p0v[4], p1v[4];
#pragma unroll
            for (int r = 0; r < 4; ++r) {
                const int qrow = qbase + quad * 4 + r;
                float a0 = (kvs + l16 > qrow) ? -1e30f : s0[r];
                float a1 = (kvs + 16 + l16 > qrow) ? -1e30f : s1[r];
                float mx = fmaxf(a0, a1);
#pragma unroll
                for (int m = 8; m; m >>= 1) mx = fmaxf(mx, __shfl_xor(mx, m, 64));
                const float mnew = fmaxf(m_i[r], mx);
                const float a = __expf(m_i[r] - mnew);
                const float p0 = __expf(a0 - mnew);
                const float p1 = __expf(a1 - mnew);
                float ps = p0 + p1;
#pragma unroll
                for (int m = 8; m; m >>= 1) ps += __shfl_xor(ps, m, 64);
                l_i[r] = l_i[r] * a + ps;
                m_i[r] = mnew;
                alpha[r] = a; p0v[r] = p0; p1v[r] = p1;
            }
#pragma unroll
            for (int t = 0; t < 16; ++t) {
                f32x4 o = o_acc[t];
                o[0] *= alpha[0]; o[1] *= alpha[1]; o[2] *= alpha[2]; o[3] *= alpha[3];
                o_acc[t] = o;
            }
            bf16* pw = &Pw[wave * 16 * 40];
#pragma unroll
            for (int r = 0; r < 4; ++r) {
                pw[(quad * 4 + r) * 40 + l16]      = (bf16)p0v[r];
                pw[(quad * 4 + r) * 40 + 16 + l16] = (bf16)p1v[r];
            }
            __syncthreads();
            const bf16x8 pa = *(const bf16x8*)(&pw[l16 * 40 + quad * 8]);
#pragma unroll
            for (int t = 0; t < 16; ++t) {
                bf16x8 vfr = *(const bf16x8*)(&Vt[(t * 16 + l16) * 40 + quad * 8]);
                o_acc[t] = mfma16(pa, vfr, o_acc[t]);
            }
            __syncthreads();
        }

        // fused gating epilogue: ag[(b,row,h*256+d)] = bf16(o * sigmoid(gate))
#pragma unroll
        for (int r = 0; r < 4; ++r) {
            const float inv = 1.f / l_i[r];
            const int row = qbase + quad * 4 + r;
            const float* gr = qg + ((size_t)((b * 2048 + row) * 8 + h)) * 512 + 256;
            bf16* ar = ag + ((size_t)(b * 2048 + row)) * 2048 + h * 256;
#pragma unroll
            for (int t = 0; t < 16; ++t) {
                const int d = t * 16 + l16;
                const float o = o_acc[t][r] * inv;
                const float gg = gr[d];
                ar[d] = (bf16)(o * (1.f / (1.f + __expf(-gg))));
            }
        }
    }
}

// ---------------------------------------------------------------------------
extern "C" void kernel_launch(void* const* d_in, const int* in_sizes, int n_in,
                              void* d_out, int out_size, void* d_ws, size_t ws_size,
                              hipStream_t stream)
{
    const float* emb       = (const float*)d_in[0];
    const float* hid       = (const float*)d_in[1];
    const float* pre_emb_w = (const float*)d_in[2];
    const float* pre_hid_w = (const float*)d_in[3];
    const float* fc_w      = (const float*)d_in[4];
    const float* in_ln_w   = (const float*)d_in[5];
    const float* q_w       = (const float*)d_in[6];
    const float* k_w       = (const float*)d_in[7];
    const float* v_w       = (const float*)d_in[8];
    const float* o_w       = (const float*)d_in[9];
    const float* qn_w      = (const float*)d_in[10];
    const float* kn_w      = (const float*)d_in[11];
    const float* post_ln_w = (const float*)d_in[12];
    const float* gate_w    = (const float*)d_in[13];
    const float* up_w      = (const float*)d_in[14];
    const float* down_w    = (const float*)d_in[15];
    const float* norm_w    = (const float*)d_in[16];
    const float* lm_w      = (const float*)d_in[17];
    float* out = (float*)d_out;
    char* ws = (char*)d_ws;

    // workspace layout (lifetime-overlapped), total 360 MiB (unchanged)
    float* xres = (float*)(ws + 0);                 // 32 MiB, residual (in-place)
    bf16*  xln  = (bf16*)(ws + 33554432);           // 16 MiB, reused 3x
    char*  C    = ws + 50331648;                    // 128 MiB: qg then gf (+ wb slots)
    char*  D    = ws + 184549376;                   // 128 MiB: xcat/kvf then ag
    char*  E    = ws + 318767104;                   // 56 MiB: qa/ka/va then hb
    float* qg   = (float*)C;
    float* gf   = (float*)C;
    bf16*  xcat = (bf16*)D;
    float* kvf  = (float*)(D + 33554432);    // 32 MiB merged k|v GEMM out (8192x1024)
    bf16*  ag   = (bf16*)(D + 67108864);     // 32 MiB
    bf16*  qa   = (bf16*)E;
    bf16*  ka   = (bf16*)(E + 33554432);
    bf16*  va   = (bf16*)(E + 41943040);
    bf16*  hb   = (bf16*)E;                  // 56 MiB, written after qa/ka/va dead
    // bf16 weight scratch slots (placed in regions dead at time of use)
    bf16*  wbC  = (bf16*)C;                  // fc(4M), o(4M), down(7M), lm(32M)
    bf16*  wbD  = (bf16*)D;                  // q(8M) + k(1M) + v(1M) @ D+0..10M
    bf16*  wkv  = (bf16*)D + 4194304;        // k|v rows (1024x1024 bf16)
    bf16*  wbDt = (bf16*)(D + 117440512);    // gate(7M) + up(7M)

    prenorm_kernel<<<4096, 256, 0, stream>>>(emb, hid, pre_emb_w, pre_hid_w, xcat);

    w2b_kernel<<<2048, 256, 0, stream>>>(fc_w, wbC);                       // 1024x2048
    gemm_kernel<0><<<512, 256, 0, stream>>>(xcat, wbC, nullptr, xres, 8192, 1024, 2048);
    rmsnorm_kernel<<<2048, 256, 0, stream>>>(xres, in_ln_w, xln);

    w2b_qkv_kernel<<<5120, 256, 0, stream>>>(q_w, k_w, v_w, wbD);
    gemm256_kernel<0><<<512, 512, 0, stream>>>(xln, wbD, nullptr, qg, nullptr, 8192, 4096, 1024);
    gemm_kernel<0><<<512, 256, 0, stream>>>(xln, wkv, nullptr, kvf, 8192, 1024, 1024);  // merged k|v

    qprep_kernel<<<16384, 256, 0, stream>>>(qg, qn_w, qa);
    kprep_kernel<<<4096, 256, 0, stream>>>(kvf, kn_w, ka);
    vprep_kernel<<<dim3(32, 4, 8), 256, 0, stream>>>(kvf, va);
    attn_kernel<<<512, 256, 0, stream>>>(qa, ka, va, qg, ag);   // fused gating

    w2b_kernel<<<2048, 256, 0, stream>>>(o_w, wbC);                        // 1024x2048
    gemm_kernel<1><<<512, 256, 0, stream>>>(ag, wbC, xres, xres, 8192, 1024, 2048);
    rmsnorm_kernel<<<2048, 256, 0, stream>>>(xres, post_ln_w, xln);

    w2b_gu_kernel<<<7168, 256, 0, stream>>>(gate_w, up_w, wbDt);
    gemm256_kernel<0><<<448, 512, 0, stream>>>(xln, wbDt, nullptr, gf, nullptr, 8192, 3584, 1024);
    gemm256_kernel<2><<<448, 512, 0, stream>>>(xln, wbDt + 3670016, gf, nullptr, hb, 8192, 3584, 1024);

    w2b_kernel<<<3584, 256, 0, stream>>>(down_w, wbC);                     // 1024x3584
    gemm_kernel<1><<<512, 256, 0, stream>>>(hb, wbC, xres, xres, 8192, 1024, 3584);
    rmsnorm_kernel<<<2048, 256, 0, stream>>>(xres, norm_w, xln);

    w2b_kernel<<<16384, 256, 0, stream>>>(lm_w, wbC);                      // 16384x1024
    gemm256_kernel<0><<<2048, 512, 0, stream>>>(xln, wbC, nullptr, out, nullptr, 8192, 16384, 1024);
}

// Round 8
// 1709.685 us; speedup vs baseline: 1.1234x; 1.0108x over previous
//
#include <hip/hip_runtime.h>

typedef __bf16 bf16;
typedef __bf16 bf16x8 __attribute__((ext_vector_type(8)));
typedef __bf16 bf16x4 __attribute__((ext_vector_type(4)));
typedef float f32x4 __attribute__((ext_vector_type(4)));

__device__ inline f32x4 mfma16(bf16x8 a, bf16x8 b, f32x4 c) {
    return __builtin_amdgcn_mfma_f32_16x16x32_bf16(a, b, c, 0, 0, 0);
}

// async global->LDS, 16B per lane. LDS dest is wave-uniform base + lane*16.
__device__ __forceinline__ void async_cp16(const void* g, void* l) {
    __builtin_amdgcn_global_load_lds(
        (__attribute__((address_space(1))) char*)g,
        (__attribute__((address_space(3))) char*)l,
        16, 0, 0);
}

// f32 -> bf16 weight conversion, vec4. grid = n/1024 blocks.
__global__ __launch_bounds__(256) void w2b_kernel(const float* __restrict__ s,
                                                  bf16* __restrict__ d)
{
    const size_t i = ((size_t)blockIdx.x * 256 + threadIdx.x) * 4;
    const float4 f = *(const float4*)(s + i);
    bf16x4 t;
    t[0] = (bf16)f.x; t[1] = (bf16)f.y; t[2] = (bf16)f.z; t[3] = (bf16)f.w;
    *(bf16x4*)(d + i) = t;
}

// merged q/k/v weight conversion: q(4096 blk) -> dq, k(512) -> dq+4M, v(512) -> +4.5M
__global__ __launch_bounds__(256) void w2b_qkv_kernel(
    const float* __restrict__ qw, const float* __restrict__ kw,
    const float* __restrict__ vw, bf16* __restrict__ dq)
{
    int bid = blockIdx.x;
    const float* s; bf16* d;
    if (bid < 4096)      { s = qw; d = dq; }
    else if (bid < 4608) { s = kw; d = dq + 4194304; bid -= 4096; }
    else                 { s = vw; d = dq + 4718592; bid -= 4608; }
    const size_t i = ((size_t)bid * 256 + threadIdx.x) * 4;
    const float4 f = *(const float4*)(s + i);
    bf16x4 t;
    t[0] = (bf16)f.x; t[1] = (bf16)f.y; t[2] = (bf16)f.z; t[3] = (bf16)f.w;
    *(bf16x4*)(d + i) = t;
}

// merged gate/up weight conversion: gate(3584 blk) -> dg, up(3584) -> dg+3.5M
__global__ __launch_bounds__(256) void w2b_gu_kernel(
    const float* __restrict__ gw, const float* __restrict__ uw, bf16* __restrict__ dg)
{
    int bid = blockIdx.x;
    const float* s; bf16* d;
    if (bid < 3584) { s = gw; d = dg; }
    else            { s = uw; d = dg + 3670016; bid -= 3584; }
    const size_t i = ((size_t)bid * 256 + threadIdx.x) * 4;
    const float4 f = *(const float4*)(s + i);
    bf16x4 t;
    t[0] = (bf16)f.x; t[1] = (bf16)f.y; t[2] = (bf16)f.z; t[3] = (bf16)f.w;
    *(bf16x4*)(d + i) = t;
}

// ---------------------------------------------------------------------------
// 128x128-tile GEMM v3: BK=64, XOR swizzle, + T3-minimum prefetch pipeline:
// double-buffered LDS (64 KiB; these GEMMs are grid-limited to 2 blocks/CU so
// the extra LDS is free), next tile's global_load_lds issued BEFORE the
// current tile's reads+MFMA, single drain+barrier per tile. Hazards: buf n's
// readers (tile t-1 = buf c(t-1)=n) drain via lgkm before that tile's end
// barrier; STG(n) at t comes after it. Reads of buf c at t follow the barrier
// that drained STG(c) issued at t-1.
// C(MxN) = A(MxK)bf16 @ B(NxK)bf16^T, f32 accum. EPI1 adds residual.
// ---------------------------------------------------------------------------
template <int EPI>
__global__ __launch_bounds__(256) void gemm_kernel(
    const bf16* __restrict__ A, const bf16* __restrict__ B,
    const float* __restrict__ res, float* __restrict__ Cout,
    int M, int N, int K)
{
    __shared__ bf16 As[2][128][64];
    __shared__ bf16 Bs[2][128][64];
    const int tid = threadIdx.x;
    const int wave = tid >> 6, lane = tid & 63;
    const int quad = lane >> 4, l16 = lane & 15;
    const int xsw = l16 & 7;

    const int nby = M >> 7, nbx = N >> 7;
    const int nwg = nbx * nby;
    int bid = blockIdx.x;
    {
        const int q = nwg >> 3, r = nwg & 7;
        const int x = bid & 7, loc = bid >> 3;
        bid = (x < r ? x * (q + 1) : r * (q + 1) + (x - r) * q) + loc;
    }
    const int pg = nbx << 3;
    const int g = bid / pg, rem = bid - g * pg;
    const int by = (g << 3) + (rem & 7);
    const int bx = rem >> 3;
    const int row0 = by << 7, col0 = bx << 7;
    const int wrow = ((wave >> 1) << 6), wcol = ((wave & 1) << 6);

    f32x4 acc[4][4] = {};

    // staging: thread t -> row t>>3 (+32 per call), chunk (t&7)^(row&7)
    const int srow = tid >> 3;
    const int scol = ((tid & 7) ^ (srow & 7)) * 8;
    const bf16* Ag = A + (size_t)(row0 + srow) * K + scol;
    const bf16* Bg = B + (size_t)(col0 + srow) * K + scol;
    const size_t K32 = (size_t)32 * K;

#define STG128(BUF, KB) do { \
    _Pragma("unroll") for (int q = 0; q < 4; ++q) { \
        async_cp16(Ag + q * K32 + (KB), &As[BUF][0][0] + q * 2048 + wave * 512); \
        async_cp16(Bg + q * K32 + (KB), &Bs[BUF][0][0] + q * 2048 + wave * 512); } } while (0)

    const int NT = K >> 6;
    STG128(0, 0);
    __syncthreads();
    for (int t = 0; t < NT; ++t) {
        const int c = t & 1, n = c ^ 1;
        if (t + 1 < NT) STG128(n, (t + 1) * 64);   // in flight under this tile's compute
        bf16x8 af[8], bfr[8];
#pragma unroll
        for (int i = 0; i < 4; ++i) {
            af[i * 2 + 0] = *(const bf16x8*)(&As[c][wrow + i * 16 + l16][(quad ^ xsw) * 8]);
            af[i * 2 + 1] = *(const bf16x8*)(&As[c][wrow + i * 16 + l16][((4 + quad) ^ xsw) * 8]);
        }
#pragma unroll
        for (int j = 0; j < 4; ++j) {
            bfr[j * 2 + 0] = *(const bf16x8*)(&Bs[c][wcol + j * 16 + l16][(quad ^ xsw) * 8]);
            bfr[j * 2 + 1] = *(const bf16x8*)(&Bs[c][wcol + j * 16 + l16][((4 + quad) ^ xsw) * 8]);
        }
#pragma unroll
        for (int i = 0; i < 4; ++i)
#pragma unroll
            for (int j = 0; j < 4; ++j) {
                acc[i][j] = mfma16(af[i * 2 + 0], bfr[j * 2 + 0], acc[i][j]);
                acc[i][j] = mfma16(af[i * 2 + 1], bfr[j * 2 + 1], acc[i][j]);
            }
        __syncthreads();   // drains prefetch (residual latency only) + barrier
    }
#undef STG128

#pragma unroll
    for (int i = 0; i < 4; ++i) {
        const int row = row0 + wrow + i * 16 + quad * 4;
#pragma unroll
        for (int j = 0; j < 4; ++j) {
            const int col = col0 + wcol + j * 16 + l16;
#pragma unroll
            for (int r = 0; r < 4; ++r) {
                const size_t idx = (size_t)(row + r) * N + col;
                float v = acc[i][j][r];
                if (EPI == 1) Cout[idx] = v + res[idx];
                else          Cout[idx] = v;
            }
        }
    }
}

// ---------------------------------------------------------------------------
// 256x256-tile GEMM, v3: 2-barrier counted-pipeline per K-tile (see R4 notes).
// EPI: 0 = f32 out; 1 = f32 out + residual; 2 = hout = bf16(silu(res)*acc)
// ---------------------------------------------------------------------------
template <int EPI>
__global__ __launch_bounds__(512, 2) void gemm256_kernel(
    const bf16* __restrict__ A, const bf16* __restrict__ B,
    const float* __restrict__ res, float* __restrict__ Cout,
    bf16* __restrict__ hout, int M, int N, int K)
{
    __shared__ bf16 As[2][2][128][64];
    __shared__ bf16 Bs[2][2][128][64];
    const int tid = threadIdx.x;
    const int wid = tid >> 6, lane = tid & 63;
    const int quad = lane >> 4, l16 = lane & 15;
    const int wm = wid >> 2, wn = wid & 3;
    const int xsw = l16 & 7;
    const int bofs = (wn & 1) * 64;

    const int nby = M >> 8, nbx = N >> 8;
    const int nwg = nbx * nby;
    int bid = blockIdx.x;
    {
        const int q = nwg >> 3, r = nwg & 7;
        const int x = bid & 7, loc = bid >> 3;
        bid = (x < r ? x * (q + 1) : r * (q + 1) + (x - r) * q) + loc;
    }
    const int pg = nbx << 3;
    const int g = bid / pg, rem = bid - g * pg;
    const int by = (g << 3) + (rem & 7);
    const int bx = rem >> 3;
    const int row0 = by << 8, col0 = bx << 8;

    const int srow = tid >> 3;
    const int scol = ((tid & 7) ^ ((tid >> 3) & 7)) * 8;
    const bf16* Abase = A + (size_t)(row0 + srow) * K + scol;
    const bf16* Bbase = B + (size_t)(col0 + srow) * K + scol;
    const size_t K64 = (size_t)K * 64;
    const size_t K128 = (size_t)K * 128;

    f32x4 acc[8][4] = {};
    bf16x8 af[8], bf0[4], bf1[4];

#define STG_A(BUF, HH, KB) do { \
    const bf16* _g = Abase + (size_t)(HH) * K128 + (KB); \
    bf16* _l = &As[BUF][HH][0][0] + wid * 512; \
    async_cp16(_g, _l); \
    async_cp16(_g + K64, _l + 4096); } while (0)
#define STG_B(BUF, HH, KB) do { \
    const bf16* _g = Bbase + (size_t)(HH) * K128 + (KB); \
    bf16* _l = &Bs[BUF][HH][0][0] + wid * 512; \
    async_cp16(_g, _l); \
    async_cp16(_g + K64, _l + 4096); } while (0)

#define RD_A(BUF, RH) do { \
    const bf16 (*Ah_)[64] = As[BUF][wm]; \
    _Pragma("unroll") for (int f = 0; f < 4; ++f) { \
        af[f*2+0] = *(const bf16x8*)(&Ah_[(RH)*64 + f*16 + l16][(quad ^ xsw) * 8]); \
        af[f*2+1] = *(const bf16x8*)(&Ah_[(RH)*64 + f*16 + l16][((4 + quad) ^ xsw) * 8]); } } while (0)

#define RD_B(BUF, CH, BF) do { \
    const bf16 (*Bh_)[64] = Bs[BUF][wn >> 1]; \
    _Pragma("unroll") for (int f = 0; f < 2; ++f) { \
        BF[f*2+0] = *(const bf16x8*)(&Bh_[bofs + (CH)*32 + f*16 + l16][(quad ^ xsw) * 8]); \
        BF[f*2+1] = *(const bf16x8*)(&Bh_[bofs + (CH)*32 + f*16 + l16][((4 + quad) ^ xsw) * 8]); } } while (0)

#define MFMA_Q(RH, CH, BF) do { \
    _Pragma("unroll") for (int f = 0; f < 4; ++f) \
    _Pragma("unroll") for (int f2 = 0; f2 < 2; ++f2) { \
        acc[(RH)*4+f][(CH)*2+f2] = mfma16(af[f*2+0], BF[f2*2+0], acc[(RH)*4+f][(CH)*2+f2]); \
        acc[(RH)*4+f][(CH)*2+f2] = mfma16(af[f*2+1], BF[f2*2+1], acc[(RH)*4+f][(CH)*2+f2]); } } while (0)

    const int NT = K >> 6;
    STG_A(0, 0, 0); STG_A(0, 1, 0); STG_B(0, 0, 0); STG_B(0, 1, 0);
    if (NT > 1) {
        STG_A(1, 0, 64); STG_A(1, 1, 64); STG_B(1, 0, 64); STG_B(1, 1, 64);
        asm volatile("s_waitcnt vmcnt(8)" ::: "memory");
    } else {
        asm volatile("s_waitcnt vmcnt(0)" ::: "memory");
    }
    __builtin_amdgcn_sched_barrier(0);
    __builtin_amdgcn_s_barrier();
    RD_A(0, 0); RD_B(0, 0, bf0); RD_B(0, 1, bf1);
    __builtin_amdgcn_sched_barrier(0);

    for (int t = 0; t < NT; ++t) {
        const int c = t & 1, n = c ^ 1;
        const int kb1 = (t + 1) << 6, kb2 = (t + 2) << 6;
        // ---------------- phase A ----------------
        if (t >= 1 && t + 1 < NT) { STG_A(n, 0, kb1); STG_A(n, 1, kb1); }
        asm volatile("s_waitcnt lgkmcnt(4)" ::: "memory");   // af0+bf0 ready
        __builtin_amdgcn_sched_barrier(0);
        __builtin_amdgcn_s_setprio(1);
        MFMA_Q(0, 0, bf0);
        __builtin_amdgcn_s_setprio(0);
        asm volatile("s_waitcnt lgkmcnt(0)" ::: "memory");   // bf1 ready
        __builtin_amdgcn_sched_barrier(0);
        __builtin_amdgcn_s_setprio(1);
        MFMA_Q(0, 1, bf1);
        __builtin_amdgcn_s_setprio(0);
        RD_A(c, 1);                                          // af1: hides under Q01 drain
        __builtin_amdgcn_sched_barrier(0);
        __builtin_amdgcn_s_barrier();                        // BAR1
        // ---------------- phase B ----------------
        if (t + 2 < NT) { STG_B(c, 0, kb2); STG_B(c, 1, kb2); }
        asm volatile("s_waitcnt lgkmcnt(0)" ::: "memory");   // af1 ready
        __builtin_amdgcn_sched_barrier(0);
        __builtin_amdgcn_s_setprio(1);
        MFMA_Q(1, 0, bf0);
        MFMA_Q(1, 1, bf1);
        __builtin_amdgcn_s_setprio(0);
        if (t + 1 < NT) {
            if (t + 2 < NT) { asm volatile("s_waitcnt vmcnt(4)" ::: "memory"); }
            else            { asm volatile("s_waitcnt vmcnt(0)" ::: "memory"); }
            __builtin_amdgcn_sched_barrier(0);
            RD_A(n, 0); RD_B(n, 0, bf0); RD_B(n, 1, bf1);    // next tile's operands
            __builtin_amdgcn_sched_barrier(0);
        }
        __builtin_amdgcn_s_barrier();                        // BAR2
    }
#undef STG_A
#undef STG_B
#undef RD_A
#undef RD_B
#undef MFMA_Q

#pragma unroll
    for (int fr = 0; fr < 8; ++fr) {
        const int row = row0 + wm * 128 + fr * 16 + quad * 4;
#pragma unroll
        for (int fc = 0; fc < 4; ++fc) {
            const int col = col0 + wn * 64 + fc * 16 + l16;
#pragma unroll
            for (int r = 0; r < 4; ++r) {
                const size_t idx = (size_t)(row + r) * N + col;
                float v = acc[fr][fc][r];
                if (EPI == 1) {
                    Cout[idx] = v + res[idx];
                } else if (EPI == 2) {
                    const float gg = res[idx];
                    hout[idx] = (bf16)(gg * (1.f / (1.f + __expf(-gg))) * v);
                } else {
                    Cout[idx] = v;
                }
            }
        }
    }
}

// ---------------------------------------------------------------------------
// prenorm+concat: xcat[row,0:1024]=rmsnorm(emb), [1024:2048]=rmsnorm(hid)
// ---------------------------------------------------------------------------
__global__ __launch_bounds__(256) void prenorm_kernel(
    const float* __restrict__ emb, const float* __restrict__ hid,
    const float* __restrict__ we, const float* __restrict__ wh,
    bf16* __restrict__ xcat)
{
    const int rr = blockIdx.x * 4 + (threadIdx.x >> 6);
    const int lane = threadIdx.x & 63;
    const int half = rr & 1, row = rr >> 1;
    const float* x = (half ? hid : emb) + (size_t)row * 1024;
    const float* w = half ? wh : we;
    float4 v[4]; float ss = 0.f;
#pragma unroll
    for (int j = 0; j < 4; ++j) {
        v[j] = *(const float4*)(x + (size_t)(lane + 64 * j) * 4);
        ss += v[j].x * v[j].x + v[j].y * v[j].y + v[j].z * v[j].z + v[j].w * v[j].w;
    }
#pragma unroll
    for (int m = 32; m; m >>= 1) ss += __shfl_xor(ss, m, 64);
    const float rms = rsqrtf(ss * (1.f / 1024.f) + 1e-6f);
    bf16* o = xcat + (size_t)row * 2048 + half * 1024;
#pragma unroll
    for (int j = 0; j < 4; ++j) {
        const int d = (lane + 64 * j) * 4;
        float4 wv = *(const float4*)(w + d);
        bf16x4 t;
        t[0] = (bf16)(v[j].x * rms * wv.x);
        t[1] = (bf16)(v[j].y * rms * wv.y);
        t[2] = (bf16)(v[j].z * rms * wv.z);
        t[3] = (bf16)(v[j].w * rms * wv.w);
        *(bf16x4*)(o + d) = t;
    }
}

// rmsnorm over H=1024, f32 in -> bf16 out, one wave per row
__global__ __launch_bounds__(256) void rmsnorm_kernel(
    const float* __restrict__ xin, const float* __restrict__ w, bf16* __restrict__ out)
{
    const int row = blockIdx.x * 4 + (threadIdx.x >> 6);
    const int lane = threadIdx.x & 63;
    const float* x = xin + (size_t)row * 1024;
    float4 v[4]; float ss = 0.f;
#pragma unroll
    for (int j = 0; j < 4; ++j) {
        v[j] = *(const float4*)(x + (size_t)(lane + 64 * j) * 4);
        ss += v[j].x * v[j].x + v[j].y * v[j].y + v[j].z * v[j].z + v[j].w * v[j].w;
    }
#pragma unroll
    for (int m = 32; m; m >>= 1) ss += __shfl_xor(ss, m, 64);
    const float rms = rsqrtf(ss * (1.f / 1024.f) + 1e-6f);
    bf16* o = out + (size_t)row * 1024;
#pragma unroll
    for (int j = 0; j < 4; ++j) {
        const int d = (lane + 64 * j) * 4;
        float4 wv = *(const float4*)(w + d);
        bf16x4 t;
        t[0] = (bf16)(v[j].x * rms * wv.x);
        t[1] = (bf16)(v[j].y * rms * wv.y);
        t[2] = (bf16)(v[j].z * rms * wv.z);
        t[3] = (bf16)(v[j].w * rms * wv.w);
        *(bf16x4*)(o + d) = t;
    }
}

// ---------------------------------------------------------------------------
// q prep, vectorized: one float4 per lane (d = 4*lane..4*lane+3).
// ---------------------------------------------------------------------------
__global__ __launch_bounds__(256) void qprep_kernel(
    const float* __restrict__ qg, const float* __restrict__ qn_w, bf16* __restrict__ qa)
{
    const int row = blockIdx.x * 4 + (threadIdx.x >> 6);  // (b*L+l)*8+h
    const int lane = threadIdx.x & 63;
    const int h = row & 7, bl = row >> 3;
    const int l = bl & 2047, b = bl >> 11;
    const float* x = qg + (size_t)row * 512;
    float4 v = *(const float4*)(x + lane * 4);
    float ss = v.x * v.x + v.y * v.y + v.z * v.z + v.w * v.w;
#pragma unroll
    for (int m = 32; m; m >>= 1) ss += __shfl_xor(ss, m, 64);
    const float rms = rsqrtf(ss * (1.f / 256.f) + 1e-6f);
    const float4 wv = *(const float4*)(qn_w + lane * 4);
    float y0 = v.x * rms * wv.x, y1 = v.y * rms * wv.y;
    float y2 = v.z * rms * wv.z, y3 = v.w * rms * wv.w;
    if (lane < 16) {
        const float inv0 = powf(1e7f, -(float)(4 * lane) * (1.f / 64.f));
        const float inv1 = powf(1e7f, -(float)(4 * lane + 2) * (1.f / 64.f));
        const float a0 = (float)l * inv0, a1 = (float)l * inv1;
        const float c0 = cosf(a0), s0 = sinf(a0), c1 = cosf(a1), s1 = sinf(a1);
        const float r0 = y0 * c0 - y1 * s0, r1 = y0 * s0 + y1 * c0;
        const float r2 = y2 * c1 - y3 * s1, r3 = y2 * s1 + y3 * c1;
        y0 = r0; y1 = r1; y2 = r2; y3 = r3;
    }
    bf16* o = qa + ((size_t)((b * 8 + h) * 2048 + l)) * 256 + lane * 4;
    bf16x4 t;
    t[0] = (bf16)(y0 * 0.0625f); t[1] = (bf16)(y1 * 0.0625f);
    t[2] = (bf16)(y2 * 0.0625f); t[3] = (bf16)(y3 * 0.0625f);
    *(bf16x4*)o = t;
}

// k prep, vectorized: same minus scale; kvf rows 1024 wide (merged k|v out).
__global__ __launch_bounds__(256) void kprep_kernel(
    const float* __restrict__ kvf, const float* __restrict__ kn_w, bf16* __restrict__ ka)
{
    const int row = blockIdx.x * 4 + (threadIdx.x >> 6);  // (b*L+l)*2+kv
    const int lane = threadIdx.x & 63;
    const int kv = row & 1, bl = row >> 1;
    const int l = bl & 2047, b = bl >> 11;
    const float* x = kvf + (size_t)bl * 1024 + kv * 256;
    float4 v = *(const float4*)(x + lane * 4);
    float ss = v.x * v.x + v.y * v.y + v.z * v.z + v.w * v.w;
#pragma unroll
    for (int m = 32; m; m >>= 1) ss += __shfl_xor(ss, m, 64);
    const float rms = rsqrtf(ss * (1.f / 256.f) + 1e-6f);
    const float4 wv = *(const float4*)(kn_w + lane * 4);
    float y0 = v.x * rms * wv.x, y1 = v.y * rms * wv.y;
    float y2 = v.z * rms * wv.z, y3 = v.w * rms * wv.w;
    if (lane < 16) {
        const float inv0 = powf(1e7f, -(float)(4 * lane) * (1.f / 64.f));
        const float inv1 = powf(1e7f, -(float)(4 * lane + 2) * (1.f / 64.f));
        const float a0 = (float)l * inv0, a1 = (float)l * inv1;
        const float c0 = cosf(a0), s0 = sinf(a0), c1 = cosf(a1), s1 = sinf(a1);
        const float r0 = y0 * c0 - y1 * s0, r1 = y0 * s0 + y1 * c0;
        const float r2 = y2 * c1 - y3 * s1, r3 = y2 * s1 + y3 * c1;
        y0 = r0; y1 = r1; y2 = r2; y3 = r3;
    }
    bf16* o = ka + ((size_t)((b * 2 + kv) * 2048 + l)) * 256 + lane * 4;
    bf16x4 t;
    t[0] = (bf16)y0; t[1] = (bf16)y1; t[2] = (bf16)y2; t[3] = (bf16)y3;
    *(bf16x4*)o = t;
}

// v prep: merged-layout (rows 1024 wide, v at col 512+kv*256+d)
// -> (B,NKV,D,L) bf16 via LDS 64x64 tile transpose.
__global__ __launch_bounds__(256) void vprep_kernel(const float* __restrict__ kvf,
                                                    bf16* __restrict__ vt)
{
    __shared__ float t[64][65];
    const int l0 = blockIdx.x << 6;
    const int d0 = blockIdx.y << 6;
    const int b = blockIdx.z >> 1, kv = blockIdx.z & 1;
    const int tx = threadIdx.x & 63, ty = threadIdx.x >> 6;
    const float* src = kvf + (size_t)b * 2048 * 1024 + 512 + kv * 256;
#pragma unroll
    for (int j = 0; j < 16; ++j) {
        const int l = ty + j * 4;
        t[l][tx] = src[(size_t)(l0 + l) * 1024 + d0 + tx];
    }
    __syncthreads();
    bf16* dst = vt + (size_t)(b * 2 + kv) * 256 * 2048;
#pragma unroll
    for (int j = 0; j < 16; ++j) {
        const int d = ty + j * 4;
        dst[(size_t)(d0 + d) * 2048 + l0 + tx] = (bf16)t[tx][d];
    }
}

// ---------------------------------------------------------------------------
// flash attention, balanced pairing + fused gating + conflict-free LDS:
//  Ks: linear [32][256] + XOR chunk swizzle (chunk ^= row&7) -> 2-way (free)
//  Vt: unpadded [256][32] -> wave reads/writes are contiguous-1KiB perms (free)
//  Pw: unpadded [16][32] per wave -> read is a contiguous-1KiB perm (free)
// (previous padded layouts measured SQ_LDS_BANK_CONFLICT = 2.2e7: ~8-way on
//  every QK and PV fragment read.)
// ---------------------------------------------------------------------------
__global__ __launch_bounds__(256) void attn_kernel(
    const bf16* __restrict__ qa, const bf16* __restrict__ ka,
    const bf16* __restrict__ vt, const float* __restrict__ qg,
    bf16* __restrict__ ag)
{
    __shared__ bf16 Ks[32 * 256];
    __shared__ bf16 Vt[256 * 32];
    __shared__ bf16 Pw[4 * 16 * 32];
    const int tid = threadIdx.x;
    const int wave = tid >> 6, lane = tid & 63;
    const int quad = lane >> 4, l16 = lane & 15;
    const int bid = blockIdx.x;
    const int j = bid & 15, h = (bid >> 4) & 7, b = bid >> 7;
    const int kvh = h >> 2;
    const bf16* qptr = qa + ((size_t)(b * 8 + h)) * 2048 * 256;
    const bf16* kptr = ka + ((size_t)(b * 2 + kvh)) * 2048 * 256;
    const bf16* vptr = vt + ((size_t)(b * 2 + kvh)) * 256 * 2048;

    for (int s = 0; s < 2; ++s) {
        const int qt = s ? (31 - j) : j;
        const int qbase = qt * 64 + wave * 16;

        bf16x8 qf[8];
#pragma unroll
        for (int db = 0; db < 8; ++db)
            qf[db] = *(const bf16x8*)(qptr + (size_t)(qbase + l16) * 256 + db * 32 + quad * 8);

        f32x4 o_acc[16] = {};
        float m_i[4], l_i[4];
#pragma unroll
        for (int r = 0; r < 4; ++r) { m_i[r] = -1e30f; l_i[r] = 0.f; }

        const int ntiles = qt * 2 + 2;
        for (int kt = 0; kt < ntiles; ++kt) {
            const int kvs = kt * 32;
#pragma unroll
            for (int c = 0; c < 4; ++c) {
                const int idx = tid + c * 256;
                const int kr = idx >> 5, kc32 = idx & 31;
                *(bf16x8*)(&Ks[kr * 256 + (kc32 ^ (kr & 7)) * 8]) =
                    *(const bf16x8*)(kptr + (size_t)(kvs + kr) * 256 + kc32 * 8);
                const int vd = idx >> 2, vc = (idx & 3) * 8;
                *(bf16x8*)(&Vt[vd * 32 + vc]) = *(const bf16x8*)(vptr + (size_t)vd * 2048 + kvs + vc);
            }
            __syncthreads();

            f32x4 s0 = {}, s1 = {};
#pragma unroll
            for (int db = 0; db < 8; ++db) {
                const int ch = (db * 4 + quad) ^ (l16 & 7);   // (16+l16)&7 == l16&7
                bf16x8 k0 = *(const bf16x8*)(&Ks[l16 * 256 + ch * 8]);
                bf16x8 k1 = *(const bf16x8*)(&Ks[(16 + l16) * 256 + ch * 8]);
                s0 = mfma16(qf[db], k0, s0);
                s1 = mfma16(qf[db], k1, s1);
            }

            float alpha[4], p0v[4], p1v[4];
#pragma unroll
            for (int r = 0; r < 4; ++r) {
                const int qrow = qbase + quad * 4 + r;
                float a0 = (kvs + l16 > qrow) ? -1e30f : s0[r];
                float a1 = (kvs + 16 + l16 > qrow) ? -1e30f : s1[r];
                float mx = fmaxf(a0, a1);
#pragma unroll
                for (int m = 8; m; m >>= 1) mx = fmaxf(mx, __shfl_xor(mx, m, 64));
                const float mnew = fmaxf(m_i[r], mx);
                const float a = __expf(m_i[r] - mnew);
                const float p0 = __expf(a0 - mnew);
                const float p1 = __expf(a1 - mnew);
                float ps = p0 + p1;
#pragma unroll
                for (int m = 8; m; m >>= 1) ps += __shfl_xor(ps, m, 64);
                l_i[r] = l_i[r] * a + ps;
                m_i[r] = mnew;
                alpha[r] = a; p0v[r] = p0; p1v[r] = p1;
            }
#pragma unroll
            for (int t = 0; t < 16; ++t) {
                f32x4 o = o_acc[t];
                o[0] *= alpha[0]; o[1] *= alpha[1]; o[2] *= alpha[2]; o[3] *= alpha[3];
                o_acc[t] = o;
            }
            bf16* pw = &Pw[wave * 16 * 32];
#pragma unroll
            for (int r = 0; r < 4; ++r) {
                pw[(quad * 4 + r) * 32 + l16]      = (bf16)p0v[r];
                pw[(quad * 4 + r) * 32 + 16 + l16] = (bf16)p1v[r];
            }
            __syncthreads();
            const bf16x8 pa = *(const bf16x8*)(&pw[l16 * 32 + quad * 8]);
#pragma unroll
            for (int t = 0; t < 16; ++t) {
                bf16x8 vfr = *(const bf16x8*)(&Vt[(t * 16 + l16) * 32 + quad * 8]);
                o_acc[t] = mfma16(pa, vfr, o_acc[t]);
            }
            __syncthreads();
        }

        // fused gating epilogue: ag[(b,row,h*256+d)] = bf16(o * sigmoid(gate))
#pragma unroll
        for (int r = 0; r < 4; ++r) {
            const float inv = 1.f / l_i[r];
            const int row = qbase + quad * 4 + r;
            const float* gr = qg + ((size_t)((b * 2048 + row) * 8 + h)) * 512 + 256;
            bf16* ar = ag + ((size_t)(b * 2048 + row)) * 2048 + h * 256;
#pragma unroll
            for (int t = 0; t < 16; ++t) {
                const int d = t * 16 + l16;
                const float o = o_acc[t][r] * inv;
                const float gg = gr[d];
                ar[d] = (bf16)(o * (1.f / (1.f + __expf(-gg))));
            }
        }
    }
}

// ---------------------------------------------------------------------------
extern "C" void kernel_launch(void* const* d_in, const int* in_sizes, int n_in,
                              void* d_out, int out_size, void* d_ws, size_t ws_size,
                              hipStream_t stream)
{
    const float* emb       = (const float*)d_in[0];
    const float* hid       = (const float*)d_in[1];
    const float* pre_emb_w = (const float*)d_in[2];
    const float* pre_hid_w = (const float*)d_in[3];
    const float* fc_w      = (const float*)d_in[4];
    const float* in_ln_w   = (const float*)d_in[5];
    const float* q_w       = (const float*)d_in[6];
    const float* k_w       = (const float*)d_in[7];
    const float* v_w       = (const float*)d_in[8];
    const float* o_w       = (const float*)d_in[9];
    const float* qn_w      = (const float*)d_in[10];
    const float* kn_w      = (const float*)d_in[11];
    const float* post_ln_w = (const float*)d_in[12];
    const float* gate_w    = (const float*)d_in[13];
    const float* up_w      = (const float*)d_in[14];
    const float* down_w    = (const float*)d_in[15];
    const float* norm_w    = (const float*)d_in[16];
    const float* lm_w      = (const float*)d_in[17];
    float* out = (float*)d_out;
    char* ws = (char*)d_ws;

    // workspace layout (lifetime-overlapped), total 360 MiB (unchanged)
    float* xres = (float*)(ws + 0);                 // 32 MiB, residual (in-place)
    bf16*  xln  = (bf16*)(ws + 33554432);           // 16 MiB, reused 3x
    char*  C    = ws + 50331648;                    // 128 MiB: qg then gf (+ wb slots)
    char*  D    = ws + 184549376;                   // 128 MiB: xcat/kvf then ag
    char*  E    = ws + 318767104;                   // 56 MiB: qa/ka/va then hb
    float* qg   = (float*)C;
    float* gf   = (float*)C;
    bf16*  xcat = (bf16*)D;
    float* kvf  = (float*)(D + 33554432);    // 32 MiB merged k|v GEMM out (8192x1024)
    bf16*  ag   = (bf16*)(D + 67108864);     // 32 MiB
    bf16*  qa   = (bf16*)E;
    bf16*  ka   = (bf16*)(E + 33554432);
    bf16*  va   = (bf16*)(E + 41943040);
    bf16*  hb   = (bf16*)E;                  // 56 MiB, written after qa/ka/va dead
    // bf16 weight scratch slots (placed in regions dead at time of use)
    bf16*  wbC  = (bf16*)C;                  // fc(4M), o(4M), down(7M), lm(32M)
    bf16*  wbD  = (bf16*)D;                  // q(8M) + k(1M) + v(1M) @ D+0..10M
    bf16*  wkv  = (bf16*)D + 4194304;        // k|v rows (1024x1024 bf16)
    bf16*  wbDt = (bf16*)(D + 117440512);    // gate(7M) + up(7M)

    prenorm_kernel<<<4096, 256, 0, stream>>>(emb, hid, pre_emb_w, pre_hid_w, xcat);

    w2b_kernel<<<2048, 256, 0, stream>>>(fc_w, wbC);                       // 1024x2048
    gemm_kernel<0><<<512, 256, 0, stream>>>(xcat, wbC, nullptr, xres, 8192, 1024, 2048);
    rmsnorm_kernel<<<2048, 256, 0, stream>>>(xres, in_ln_w, xln);

    w2b_qkv_kernel<<<5120, 256, 0, stream>>>(q_w, k_w, v_w, wbD);
    gemm256_kernel<0><<<512, 512, 0, stream>>>(xln, wbD, nullptr, qg, nullptr, 8192, 4096, 1024);
    gemm_kernel<0><<<512, 256, 0, stream>>>(xln, wkv, nullptr, kvf, 8192, 1024, 1024);  // merged k|v

    qprep_kernel<<<16384, 256, 0, stream>>>(qg, qn_w, qa);
    kprep_kernel<<<4096, 256, 0, stream>>>(kvf, kn_w, ka);
    vprep_kernel<<<dim3(32, 4, 8), 256, 0, stream>>>(kvf, va);
    attn_kernel<<<512, 256, 0, stream>>>(qa, ka, va, qg, ag);   // fused gating

    w2b_kernel<<<2048, 256, 0, stream>>>(o_w, wbC);                        // 1024x2048
    gemm_kernel<1><<<512, 256, 0, stream>>>(ag, wbC, xres, xres, 8192, 1024, 2048);
    rmsnorm_kernel<<<2048, 256, 0, stream>>>(xres, post_ln_w, xln);

    w2b_gu_kernel<<<7168, 256, 0, stream>>>(gate_w, up_w, wbDt);
    gemm256_kernel<0><<<448, 512, 0, stream>>>(xln, wbDt, nullptr, gf, nullptr, 8192, 3584, 1024);
    gemm256_kernel<2><<<448, 512, 0, stream>>>(xln, wbDt + 3670016, gf, nullptr, hb, 8192, 3584, 1024);

    w2b_kernel<<<3584, 256, 0, stream>>>(down_w, wbC);                     // 1024x3584
    gemm_kernel<1><<<512, 256, 0, stream>>>(hb, wbC, xres, xres, 8192, 1024, 3584);
    rmsnorm_kernel<<<2048, 256, 0, stream>>>(xres, norm_w, xln);

    w2b_kernel<<<16384, 256, 0, stream>>>(lm_w, wbC);                      // 16384x1024
    gemm256_kernel<0><<<2048, 512, 0, stream>>>(xln, wbC, nullptr, out, nullptr, 8192, 16384, 1024);
}